// Round 3
// baseline (328.473 us; speedup 1.0000x reference)
//
#include <hip/hip_runtime.h>

// CNN encoder round 3:
//  - conv_l1: 8px/thread register blocking, planar LDS, direct f32 x reads.
//  - all activations stored padded NHWC bf16 ([B][H+4][W+4][C], interior at +2):
//    MFMA conv A-loads have NO bounds checks; pads zeroed by bn_fin / zero_h1pad.
//  - BN stats partials fused into conv epilogue (deterministic per-block slots),
//    stage2 reduces; bn_fin applies affine+lrelu in place and zeroes pads.

typedef __attribute__((ext_vector_type(8))) short short8v;
typedef __attribute__((ext_vector_type(4))) float float4v;
typedef unsigned short u16;

#define LRELU_NEG 0.2f
#define BN_EPS 1e-5f

__device__ __forceinline__ float bf2f(u16 u){ union{unsigned i; float f;} v; v.i=(unsigned)u<<16; return v.f; }
__device__ __forceinline__ u16 f2bf(float f){ unsigned x=__float_as_uint(f); x += 0x7FFFu + ((x>>16)&1u); return (u16)(x>>16); }
__device__ __forceinline__ float lrelu(float v){ return v<0.f? LRELU_NEG*v : v; }

// ---------------------------------------------------------------------------
// prep: L2 per-sample meta weights [b][c=10][oc=16][32] + extended bias bl2
// ---------------------------------------------------------------------------
__global__ __launch_bounds__(256) void prep_l2m(const float* __restrict__ w12, const float* __restrict__ b12,
                                                const float* __restrict__ cw, u16* __restrict__ dst,
                                                float* __restrict__ bl2) {
  int i = blockIdx.x*256 + threadIdx.x;
  if (i < 16) bl2[i] = (i<8)? b12[i] : 0.f;
  if (i >= 16*10*16*32) return;
  int kq = i & 31, oc = (i>>5) & 15, c = (i>>9) % 10, b = i / (10*16*32);
  int ky = c >> 1, r = c & 1;
  int kk = r*32 + kq; int kx = kk >> 3, ic = kk & 7;
  float v = 0.f;
  if (kx < 5)
    v = (oc < 8) ? w12[((oc*8+ic)*5+ky)*5+kx]
                 : cw[b*1900 + 300 + ((oc-8)*8+ic)*25 + ky*5 + kx];
  dst[i] = f2bf(v);
}

// all shared-weight packs in one kernel: dst[c][oc][32], c=(ky,r), kk=r*32+kq
__device__ __forceinline__ void packw(int i, const float* __restrict__ w, u16* __restrict__ dst,
                                      int IC, int OC, int KSZ, int CPR) {
  int kq = i & 31, oc = (i>>5) % OC, c = i/(OC*32);
  int ky = c / CPR, r = c % CPR;
  int kk = r*32 + kq; int kx = kk / IC, ic = kk % IC;
  float v = (kx < KSZ) ? w[(((size_t)oc*IC + ic)*KSZ + ky)*KSZ + kx] : 0.f;
  dst[i] = f2bf(v);
}
__global__ __launch_bounds__(256) void prep_wall(const float* __restrict__ w1, const float* __restrict__ w2,
                                                 const float* __restrict__ w3, const float* __restrict__ w4,
                                                 u16* d1, u16* d2, u16* d3, u16* d4) {
  int i = blockIdx.x*256 + threadIdx.x;
  if (i < 15360) packw(i, w1, d1, 16, 32, 5, 3);
  else if (i < 66560) packw(i-15360, w2, d2, 32, 64, 5, 5);
  else if (i < 140288) packw(i-66560, w3, d3, 64, 128, 3, 6);
  else if (i < 287744) packw(i-140288, w4, d4, 128, 128, 3, 12);
}

// zero the pad frame of h1pad [16][516][516][8]
__global__ __launch_bounds__(256) void zero_h1pad(u16* __restrict__ h1) {
  int i = blockIdx.x*256 + threadIdx.x;
  if (i >= 16*4112) return;
  int b = i / 4112, p = i % 4112;
  int y, xx;
  if (p < 2064) { int r = p/516; y = (r<2)? r : 512+r; xx = p%516; }
  else          { int q = p-2064; int cidx = q&3; xx = (cidx<2)? cidx : 512+cidx; y = 2 + (q>>2); }
  short8v z = {0,0,0,0,0,0,0,0};
  *(short8v*)(h1 + (((size_t)b*516 + y)*516 + xx)*8) = z;
}

// ---------------------------------------------------------------------------
// L1: 3->8 k5 s1 p2, per-sample weights. 32x64 px tile, thread = 2rows x 4cols x 8oc.
// Reads x (NCHW f32) directly; writes h1pad interior (post-lrelu).
// ---------------------------------------------------------------------------
__global__ __launch_bounds__(256) void conv_l1(const float* __restrict__ x,
    const float* __restrict__ w11, const float* __restrict__ cw,
    const float* __restrict__ b11, u16* __restrict__ h1) {
  __shared__ float sx[3*68*37];
  __shared__ float sw[600];
  const int tid = threadIdx.x, b = blockIdx.z;
  const int tx0 = (blockIdx.x & 15) * 32, ty0 = (blockIdx.x >> 4) * 64;

  for (int e = tid; e < 3*68*36; e += 256) {
    int ic = e / 2448; int r = e % 2448; int yy = r / 36, xx = r % 36;
    int gy = ty0 + yy - 2, gx = tx0 + xx - 2;
    float v = 0.f;
    if (gy >= 0 && gy < 512 && gx >= 0 && gx < 512)
      v = x[((size_t)(b*3 + ic)*512 + gy)*512 + gx];
    sx[(ic*68 + yy)*37 + xx] = v;
  }
  for (int e = tid; e < 600; e += 256) {
    int oc = e & 7, k = e >> 3;
    int ic = k % 3, t2 = k / 3, kx = t2 % 5, ky = t2 / 5;
    sw[k*8 + oc] = (oc < 4) ? w11[((oc*3+ic)*5+ky)*5+kx]
                            : cw[b*1900 + ((oc-4)*3+ic)*25 + ky*5 + kx];
  }
  __syncthreads();

  const int px0 = (tid & 7) * 4, ry = (tid >> 3) * 2;
  float bj[8];
#pragma unroll
  for (int j = 0; j < 8; j++) bj[j] = (j < 4) ? b11[j] : 0.f;
  float acc[2][4][8];
#pragma unroll
  for (int rr = 0; rr < 2; rr++)
#pragma unroll
    for (int cc = 0; cc < 4; cc++)
#pragma unroll
      for (int j = 0; j < 8; j++) acc[rr][cc][j] = bj[j];

  for (int ky = 0; ky < 5; ky++) {
#pragma unroll
    for (int kx = 0; kx < 5; kx++)
#pragma unroll
      for (int ic = 0; ic < 3; ic++) {
        const float* wp = &sw[((ky*5+kx)*3 + ic)*8];
        float4v w0 = *(const float4v*)wp;
        float4v w1 = *(const float4v*)(wp + 4);
        float xv[2][4];
#pragma unroll
        for (int rr = 0; rr < 2; rr++)
#pragma unroll
          for (int cc = 0; cc < 4; cc++)
            xv[rr][cc] = sx[(ic*68 + ry + rr + ky)*37 + px0 + cc + kx];
#pragma unroll
        for (int rr = 0; rr < 2; rr++)
#pragma unroll
          for (int cc = 0; cc < 4; cc++) {
            float v = xv[rr][cc];
            acc[rr][cc][0] = fmaf(v, w0[0], acc[rr][cc][0]);
            acc[rr][cc][1] = fmaf(v, w0[1], acc[rr][cc][1]);
            acc[rr][cc][2] = fmaf(v, w0[2], acc[rr][cc][2]);
            acc[rr][cc][3] = fmaf(v, w0[3], acc[rr][cc][3]);
            acc[rr][cc][4] = fmaf(v, w1[0], acc[rr][cc][4]);
            acc[rr][cc][5] = fmaf(v, w1[1], acc[rr][cc][5]);
            acc[rr][cc][6] = fmaf(v, w1[2], acc[rr][cc][6]);
            acc[rr][cc][7] = fmaf(v, w1[3], acc[rr][cc][7]);
          }
      }
  }

#pragma unroll
  for (int rr = 0; rr < 2; rr++)
#pragma unroll
    for (int cc = 0; cc < 4; cc++) {
      int oy = ty0 + ry + rr, ox = tx0 + px0 + cc;
      short8v hv;
#pragma unroll
      for (int j = 0; j < 8; j++) hv[j] = (short)f2bf(lrelu(acc[rr][cc][j]));
      *(short8v*)(h1 + (((size_t)b*516 + oy + 2)*516 + ox + 2)*8) = hv;
    }
}

// ---------------------------------------------------------------------------
// Implicit-GEMM MFMA conv over PADDED NHWC input (no bounds checks).
// Writes padded output interior (pre-BN, +bias) and per-block BN partials.
// ---------------------------------------------------------------------------
template <int IC, int OC, int KSZ, int S, int P, int CPR, int NCH,
          int IPH, int IPW, int OWL, int OPH, int OPW,
          int WM, int WN, int WVM, int WVN, bool PERS>
__global__ __launch_bounds__(WVM*WVN*64) void conv_mfma(
    const u16* __restrict__ in, const u16* __restrict__ wmfma,
    const float* __restrict__ bias, u16* __restrict__ out,
    float2* __restrict__ part2) {
  constexpr int OW = 1 << OWL;
  constexpr int PADOFF = 2 - P;
  const int tid = threadIdx.x, lane = tid & 63;
  const int w = tid >> 6, wm = w % WVM, wn = w / WVM;
  const int l15 = lane & 15, sub = lane >> 4;
  const int b = blockIdx.z;
  const int px0 = blockIdx.x * (16*WM*WVM) + wm * (16*WM);
  const int oc0 = blockIdx.y * (16*WN*WVN) + wn * (16*WN);

  int oyf[WM], oxb[WM], ixb[WM];
#pragma unroll
  for (int f = 0; f < WM; f++) {
    int p = px0 + f*16;
    oyf[f] = p >> OWL;
    oxb[f] = p & (OW-1);
    ixb[f] = S*(oxb[f] + l15) + PADOFF;
  }
  const u16* inb = in + (size_t)b*IPH*IPW*IC;
  const u16* wbase = wmfma + (PERS ? (size_t)b*NCH*OC*32 : (size_t)0);

  float4v acc[WM][WN];
#pragma unroll
  for (int f = 0; f < WM; f++)
#pragma unroll
    for (int n = 0; n < WN; n++) acc[f][n] = (float4v){0.f,0.f,0.f,0.f};

#pragma unroll
  for (int ky = 0; ky < KSZ; ky++) {
#pragma unroll
    for (int r = 0; r < CPR; r++) {
      const int c = ky*CPR + r;
      const int kk0 = r*32 + sub*8;
      const int kx = kk0 / IC;
      const int icoff = kk0 % IC;
      short8v B[WN];
#pragma unroll
      for (int n = 0; n < WN; n++)
        B[n] = *(const short8v*)(wbase + ((size_t)c*OC + oc0 + n*16 + l15)*32 + sub*8);
      short8v A[WM];
#pragma unroll
      for (int f = 0; f < WM; f++) {
        int iy = S*oyf[f] + ky + PADOFF;
        A[f] = *(const short8v*)(inb + ((size_t)iy*IPW + ixb[f] + kx)*IC + icoff);
      }
#pragma unroll
      for (int f = 0; f < WM; f++)
#pragma unroll
        for (int n = 0; n < WN; n++)
          acc[f][n] = __builtin_amdgcn_mfma_f32_16x16x32_bf16(A[f], B[n], acc[f][n], 0, 0, 0);
    }
  }

  // epilogue: +bias, store bf16 interior, accumulate BN partials
  float s[WN], q[WN];
#pragma unroll
  for (int n = 0; n < WN; n++) { s[n] = 0.f; q[n] = 0.f; }
#pragma unroll
  for (int f = 0; f < WM; f++) {
    const int oxs = oxb[f] + sub*4;
    const size_t rowb = ((size_t)b*OPH + oyf[f] + 2)*OPW;
#pragma unroll
    for (int n = 0; n < WN; n++) {
      int oc = oc0 + n*16 + l15;
      float bv = bias[oc];
#pragma unroll
      for (int rr = 0; rr < 4; rr++) {
        float v = acc[f][n][rr] + bv;
        out[(rowb + oxs + rr + 2)*OC + oc] = f2bf(v);
        s[n] += v; q[n] += v*v;
      }
    }
  }
#pragma unroll
  for (int n = 0; n < WN; n++) {
    s[n] += __shfl_xor(s[n], 16); s[n] += __shfl_xor(s[n], 32);
    q[n] += __shfl_xor(q[n], 16); q[n] += __shfl_xor(q[n], 32);
  }
  __shared__ float sred[WVM*WVN][WN][16][2];
  if (sub == 0) {
#pragma unroll
    for (int n = 0; n < WN; n++) { sred[w][n][l15][0] = s[n]; sred[w][n][l15][1] = q[n]; }
  }
  __syncthreads();
  const int NBp = gridDim.x * gridDim.z;
  const int pb = blockIdx.z * gridDim.x + blockIdx.x;
  const int tot = WVN*WN*16;
  if (tid < tot) {
    int c16 = tid & 15, n = (tid >> 4) % WN, wn2 = tid / (16*WN);
    float S_ = 0.f, Q_ = 0.f;
    for (int wm2 = 0; wm2 < WVM; wm2++) {
      S_ += sred[wn2*WVM + wm2][n][c16][0];
      Q_ += sred[wn2*WVM + wm2][n][c16][1];
    }
    int c = blockIdx.y*(16*WN*WVN) + wn2*(16*WN) + n*16 + c16;
    part2[(size_t)c*NBp + pb] = make_float2(S_, Q_);
  }
}

// ---------------------------------------------------------------------------
// BN stage2: reduce per-block partials -> (scale, shift)
// ---------------------------------------------------------------------------
__global__ void bn_stage2(const float2* __restrict__ part2, const float* __restrict__ g,
                          const float* __restrict__ bb, float* __restrict__ stats,
                          int NBp, float invN) {
  int c = blockIdx.x;
  float s = 0.f, q = 0.f;
  for (int i = threadIdx.x; i < NBp; i += 64) {
    float2 p = part2[(size_t)c*NBp + i];
    s += p.x; q += p.y;
  }
  for (int o = 32; o > 0; o >>= 1) { s += __shfl_down(s, o); q += __shfl_down(q, o); }
  if (threadIdx.x == 0) {
    float m = s * invN;
    float var = q * invN - m*m;
    float sc = g[c] * rsqrtf(var + BN_EPS);
    stats[2*c] = sc;
    stats[2*c+1] = bb[c] - m*sc;
  }
}

// bn finalize in place over PADDED buffer: interior -> affine+lrelu, pads -> 0
template <int C, int PH, int PW, int HH, int WW>
__global__ __launch_bounds__(256) void bn_fin(u16* __restrict__ y, const float* __restrict__ stats,
                                              int total8) {
  int i = blockIdx.x*256 + threadIdx.x;
  if (i >= total8) return;
  size_t e = (size_t)i*8;
  int c0 = (int)(e & (C-1));
  int px = (int)(e / C);
  int xx = px % PW;
  int yy = (px / PW) % PH;
  bool interior = (yy >= 2) & (yy < 2+HH) & (xx >= 2) & (xx < 2+WW);
  short8v u = *(short8v*)(y + e);
  short8v o;
#pragma unroll
  for (int j = 0; j < 8; j++) {
    float v = bf2f((u16)u[j]) * stats[2*(c0+j)] + stats[2*(c0+j)+1];
    o[j] = interior ? (short)f2bf(lrelu(v)) : (short)0;
  }
  *(short8v*)(y + e) = o;
}

// final: lrelu(bn(y6pad interior)) NHWC bf16 -> NCHW fp32 d_out
__global__ __launch_bounds__(256) void out_k(const u16* __restrict__ y6,
                                             const float* __restrict__ stats,
                                             float* __restrict__ out) {
  int i = blockIdx.x*256 + threadIdx.x;
  if (i >= 131072) return;
  size_t e = (size_t)i*4;
  int c0 = (int)(e & 127);
  int px = (int)(e >> 7);
  int loc = px & 255, b = px >> 8;
  int y = loc >> 4, x = loc & 15;
  const u16* src = y6 + (((size_t)b*20 + y + 2)*20 + x + 2)*128 + c0;
  ushort4 u = *(const ushort4*)src;
  float vv[4] = {bf2f(u.x), bf2f(u.y), bf2f(u.z), bf2f(u.w)};
#pragma unroll
  for (int j = 0; j < 4; j++) {
    int c = c0 + j;
    float v = vv[j] * stats[2*c] + stats[2*c+1];
    out[(((size_t)b*128 + c) << 8) + loc] = lrelu(v);
  }
}

// ---------------------------------------------------------------------------
extern "C" void kernel_launch(void* const* d_in, const int* in_sizes, int n_in,
                              void* d_out, int out_size, void* d_ws, size_t ws_size,
                              hipStream_t stream) {
  const float* x    = (const float*)d_in[0];
  const float* cw   = (const float*)d_in[1];
  const float* w11  = (const float*)d_in[2];
  const float* b11  = (const float*)d_in[3];
  const float* w12  = (const float*)d_in[4];
  const float* b12  = (const float*)d_in[5];
  const float* bn1g = (const float*)d_in[6];
  const float* bn1b = (const float*)d_in[7];
  const float* c2w[4] = {(const float*)d_in[8], (const float*)d_in[12],
                         (const float*)d_in[16], (const float*)d_in[20]};
  const float* c2b[4] = {(const float*)d_in[9], (const float*)d_in[13],
                         (const float*)d_in[17], (const float*)d_in[21]};
  const float* bng[4] = {(const float*)d_in[10], (const float*)d_in[14],
                         (const float*)d_in[18], (const float*)d_in[22]};
  const float* bnb[4] = {(const float*)d_in[11], (const float*)d_in[15],
                         (const float*)d_in[19], (const float*)d_in[23]};

  char* ws = (char*)d_ws;
  // Region A [0, 68.16MB): h1pad during L1/L2; then y3..y6 pads + shared weights.
  u16* h1   = (u16*)(ws);                          // 16x516x516x8  = 68,158,464 B
  u16* y3   = (u16*)(ws);                          // 16x132x132x32 = 17,842,176
  u16* y4   = (u16*)(ws + 17842176);               // 16x68x68x64   =  9,469,952
  u16* y5   = (u16*)(ws + 27312128);               // 16x36x36x128  =  5,308,416
  u16* y6   = (u16*)(ws + 32620544);               // 16x20x20x128  =  1,638,400
  u16* wS1  = (u16*)(ws + 34258944);               // 30,720
  u16* wS2  = (u16*)(ws + 34289664);               // 102,400
  u16* wS3  = (u16*)(ws + 34392064);               // 147,456
  u16* wS4  = (u16*)(ws + 34539520);               // 294,912 -> ends 34,834,432
  // Region B: yT2pad
  u16* yT2  = (u16*)(ws + 68158464);               // 16x260x260x16 = 34,611,200 -> ends 102,769,664
  // Tail: L2 meta weights + bias + partials + stats (live alongside h1+yT2)
  u16* wl2m = (u16*)(ws + 102769664);              // 163,840
  float* bl2    = (float*)(ws + 102933504);        // 64
  float2* part2 = (float2*)(ws + 102933568);       // <= 524,288
  float* stats2 = (float*)(ws + 103457856);        // 16*2
  float* stats3 = stats2 + 32;                     // 32*2
  float* stats4 = stats3 + 64;                     // 64*2
  float* stats5 = stats4 + 128;                    // 128*2
  float* stats6 = stats5 + 256;                    // 128*2

  prep_l2m<<<320, 256, 0, stream>>>(w12, b12, cw, wl2m, bl2);

  // L1: 3->8 k5 s1 -> h1pad interior (post-lrelu); zero pad frame
  conv_l1<<<dim3(128, 1, 16), 256, 0, stream>>>(x, w11, cw, b11, h1);
  zero_h1pad<<<257, 256, 0, stream>>>(h1);

  // L2: 8->16 k5 s2, per-sample weights -> yT2pad (pre-BN) + partials
  conv_mfma<8,16,5,2,2, 2,10, 516,516, 8, 260,260, 4,1,4,1, true>
      <<<dim3(256,1,16), 256, 0, stream>>>(h1, wl2m, bl2, yT2, part2);

  // shared-weight packs (into region A — after L2 in stream order)
  prep_wall<<<1124, 256, 0, stream>>>(c2w[0], c2w[1], c2w[2], c2w[3], wS1, wS2, wS3, wS4);

  bn_stage2<<<16, 64, 0, stream>>>(part2, bn1g, bn1b, stats2, 4096, 1.f/1048576.f);
  bn_fin<16,260,260,256,256><<<8450, 256, 0, stream>>>(yT2, stats2, 2163200);

  // S1: 16->32 k5 s2 -> y3pad
  conv_mfma<16,32,5,2,2, 3,15, 260,260, 7, 132,132, 2,2,4,1, false>
      <<<dim3(128,1,16), 256, 0, stream>>>(yT2, wS1, c2b[0], y3, part2);
  bn_stage2<<<32, 64, 0, stream>>>(part2, bng[0], bnb[0], stats3, 2048, 1.f/262144.f);
  bn_fin<32,132,132,128,128><<<4356, 256, 0, stream>>>(y3, stats3, 1115136);

  // S2: 32->64 k5 s2 -> y4pad
  conv_mfma<32,64,5,2,2, 5,25, 132,132, 6, 68,68, 2,2,2,2, false>
      <<<dim3(64,1,16), 256, 0, stream>>>(y3, wS2, c2b[1], y4, part2);
  bn_stage2<<<64, 64, 0, stream>>>(part2, bng[1], bnb[1], stats4, 1024, 1.f/65536.f);
  bn_fin<64,68,68,64,64><<<2312, 256, 0, stream>>>(y4, stats4, 591872);

  // S3: 64->128 k3 s2 -> y5pad
  conv_mfma<64,128,3,2,1, 6,18, 68,68, 5, 36,36, 2,2,2,2, false>
      <<<dim3(16,2,16), 256, 0, stream>>>(y4, wS3, c2b[2], y5, part2);
  bn_stage2<<<128, 64, 0, stream>>>(part2, bng[2], bnb[2], stats5, 256, 1.f/16384.f);
  bn_fin<128,36,36,32,32><<<1296, 256, 0, stream>>>(y5, stats5, 331776);

  // S4: 128->128 k3 s2 -> y6pad (pre-BN)
  conv_mfma<128,128,3,2,1, 12,36, 36,36, 4, 20,20, 2,2,1,2, false>
      <<<dim3(8,2,16), 128, 0, stream>>>(y5, wS4, c2b[3], y6, part2);
  bn_stage2<<<128, 64, 0, stream>>>(part2, bng[3], bnb[3], stats6, 128, 1.f/4096.f);

  out_k<<<512, 256, 0, stream>>>(y6, stats6, (float*)d_out);
}

// Round 4
// 310.458 us; speedup vs baseline: 1.0580x; 1.0580x over previous
//
#include <hip/hip_runtime.h>

// CNN encoder round 4:
//  - L1 complex rebuilt: planar bf16 xpad (convert_x), conv_l1 with SGPR
//    (uniform global) weights, register row-reuse over kx, planar LDS RS=37.
//  - MFMA convs / fused BN partials / bn_fin / out_k unchanged from round 3.

typedef __attribute__((ext_vector_type(8))) short short8v;
typedef __attribute__((ext_vector_type(4))) float float4v;
typedef unsigned short u16;

#define LRELU_NEG 0.2f
#define BN_EPS 1e-5f

__device__ __forceinline__ float bf2f(u16 u){ union{unsigned i; float f;} v; v.i=(unsigned)u<<16; return v.f; }
__device__ __forceinline__ u16 f2bf(float f){ unsigned x=__float_as_uint(f); x += 0x7FFFu + ((x>>16)&1u); return (u16)(x>>16); }
__device__ __forceinline__ float lrelu(float v){ return v<0.f? LRELU_NEG*v : v; }

// ---------------------------------------------------------------------------
// prep: L2 per-sample meta weights [b][c=10][oc=16][32] bf16, bl2,
//       and L1 per-sample weights wl1f [b][ky][ic][kx][oc=8] f32.
// ---------------------------------------------------------------------------
__global__ __launch_bounds__(256) void prep_l2m(const float* __restrict__ w12, const float* __restrict__ b12,
                                                const float* __restrict__ w11, const float* __restrict__ cw,
                                                u16* __restrict__ dst, float* __restrict__ bl2,
                                                float* __restrict__ wl1f) {
  int i = blockIdx.x*256 + threadIdx.x;
  if (i < 16) bl2[i] = (i<8)? b12[i] : 0.f;
  if (i < 9600) {          // 16*600: [b][ky][ic][kx][oc]
    int b = i/600, r = i%600;
    int oc = r & 7, t = r >> 3;
    int kx = t % 5, u2 = t / 5, ic = u2 % 3, ky = u2 / 3;
    wl1f[i] = (oc < 4) ? w11[((oc*3+ic)*5+ky)*5+kx]
                       : cw[b*1900 + (oc-4)*75 + ic*25 + ky*5 + kx];
  }
  if (i >= 16*10*16*32) return;
  int kq = i & 31, oc = (i>>5) & 15, c = (i>>9) % 10, b = i / (10*16*32);
  int ky = c >> 1, r = c & 1;
  int kk = r*32 + kq; int kx = kk >> 3, ic = kk & 7;
  float v = 0.f;
  if (kx < 5)
    v = (oc < 8) ? w12[((oc*8+ic)*5+ky)*5+kx]
                 : cw[b*1900 + 300 + ((oc-8)*8+ic)*25 + ky*5 + kx];
  dst[i] = f2bf(v);
}

// all shared-weight packs in one kernel: dst[c][oc][32], c=(ky,r), kk=r*32+kq
__device__ __forceinline__ void packw(int i, const float* __restrict__ w, u16* __restrict__ dst,
                                      int IC, int OC, int KSZ, int CPR) {
  int kq = i & 31, oc = (i>>5) % OC, c = i/(OC*32);
  int ky = c / CPR, r = c % CPR;
  int kk = r*32 + kq; int kx = kk / IC, ic = kk % IC;
  float v = (kx < KSZ) ? w[(((size_t)oc*IC + ic)*KSZ + ky)*KSZ + kx] : 0.f;
  dst[i] = f2bf(v);
}
__global__ __launch_bounds__(256) void prep_wall(const float* __restrict__ w1, const float* __restrict__ w2,
                                                 const float* __restrict__ w3, const float* __restrict__ w4,
                                                 u16* d1, u16* d2, u16* d3, u16* d4) {
  int i = blockIdx.x*256 + threadIdx.x;
  if (i < 15360) packw(i, w1, d1, 16, 32, 5, 3);
  else if (i < 66560) packw(i-15360, w2, d2, 32, 64, 5, 5);
  else if (i < 140288) packw(i-66560, w3, d3, 64, 128, 3, 6);
  else if (i < 287744) packw(i-140288, w4, d4, 128, 128, 3, 12);
}

// ---------------------------------------------------------------------------
// x (NCHW f32) -> xpad planar bf16 [3][16][516][520], interior at (y+2, x+2)
// ---------------------------------------------------------------------------
__global__ __launch_bounds__(256) void convert_x(const float* __restrict__ x, u16* __restrict__ xpad) {
  int i = blockIdx.x*256 + threadIdx.x;
  if (i >= 16*3*512*64) return;
  int xseg = i & 63;
  int y = (i >> 6) & 511;
  int plane = i >> 15;               // 0..47
  int ic = plane % 3, b = plane / 3;
  const float* src = x + (((size_t)(b*3 + ic)*512 + y) << 9) + xseg*8;
  float4v f0 = *(const float4v*)src;
  float4v f1 = *(const float4v*)(src + 4);
  u16* dp = xpad + ((size_t)(ic*16 + b)*516 + y + 2)*520 + xseg*8 + 2;
  ushort2 a0 = {f2bf(f0[0]), f2bf(f0[1])};
  ushort2 a1 = {f2bf(f0[2]), f2bf(f0[3])};
  ushort2 a2 = {f2bf(f1[0]), f2bf(f1[1])};
  ushort2 a3 = {f2bf(f1[2]), f2bf(f1[3])};
  *(ushort2*)(dp+0) = a0; *(ushort2*)(dp+2) = a1;
  *(ushort2*)(dp+4) = a2; *(ushort2*)(dp+6) = a3;
}

// zero the pad frame of xpad (rows 0,1,514,515 full; cols 0,1,514..519)
__global__ __launch_bounds__(256) void zero_xpad(u16* __restrict__ xpad) {
  int i = blockIdx.x*256 + threadIdx.x;
  if (i >= 48*6176) return;
  int plane = i / 6176, r = i % 6176;
  int y, x;
  if (r < 2080) { int ridx = r/520; y = (ridx<2)? ridx : 512+ridx; x = r%520; }
  else { int q = r-2080; int cid = q & 7; x = (cid<2)? cid : 512+cid; y = 2 + (q>>3); }
  xpad[((size_t)plane*516 + y)*520 + x] = 0;
}

// zero the pad frame of h1pad [16][516][516][8]
__global__ __launch_bounds__(256) void zero_h1pad(u16* __restrict__ h1) {
  int i = blockIdx.x*256 + threadIdx.x;
  if (i >= 16*4112) return;
  int b = i / 4112, p = i % 4112;
  int y, xx;
  if (p < 2064) { int r = p/516; y = (r<2)? r : 512+r; xx = p%516; }
  else          { int q = p-2064; int cidx = q&3; xx = (cidx<2)? cidx : 512+cidx; y = 2 + (q>>2); }
  short8v z = {0,0,0,0,0,0,0,0};
  *(short8v*)(h1 + (((size_t)b*516 + y)*516 + xx)*8) = z;
}

// ---------------------------------------------------------------------------
// L1: 3->8 k5 s1 p2, per-sample weights (SGPR path). 32x32 px tile/block,
// thread = 1 row x 4 cols x 8 oc; register row-window reuse over kx.
// ---------------------------------------------------------------------------
__global__ __launch_bounds__(256) void conv_l1(const u16* __restrict__ xpad,
    const float* __restrict__ wl1f, const float* __restrict__ b11,
    u16* __restrict__ h1) {
  __shared__ float sx[3*36*37];
  const int tid = threadIdx.x, b = blockIdx.z;
  const int tx0 = (blockIdx.x & 15) * 32, ty0 = (blockIdx.x >> 4) * 32;

  for (int e = tid; e < 972; e += 256) {
    int r = e / 9, j = e % 9;
    int ic = r / 36, yy = r % 36;
    ushort4 u = *(const ushort4*)(xpad + ((size_t)(ic*16 + b)*516 + ty0 + yy)*520 + tx0 + 4*j);
    float* dp = &sx[(ic*36 + yy)*37 + 4*j];
    dp[0] = bf2f(u.x); dp[1] = bf2f(u.y); dp[2] = bf2f(u.z); dp[3] = bf2f(u.w);
  }
  __syncthreads();

  const float* __restrict__ wb = wl1f + b*600;   // uniform per block -> s_load
  const int y = tid >> 3, x0 = (tid & 7) * 4;

  float acc[4][8];
#pragma unroll
  for (int cc = 0; cc < 4; cc++)
#pragma unroll
    for (int j = 0; j < 8; j++) acc[cc][j] = (j < 4) ? b11[j] : 0.f;

  for (int ky = 0; ky < 5; ky++) {
#pragma unroll
    for (int ic = 0; ic < 3; ic++) {
      const float* sp = &sx[(ic*36 + y + ky)*37 + x0];
      float xr[8];
#pragma unroll
      for (int j = 0; j < 8; j++) xr[j] = sp[j];
#pragma unroll
      for (int kx = 0; kx < 5; kx++) {
        const float* wp = wb + ((ky*3 + ic)*5 + kx)*8;
#pragma unroll
        for (int j = 0; j < 8; j++) {
          float wv = wp[j];
#pragma unroll
          for (int cc = 0; cc < 4; cc++)
            acc[cc][j] = fmaf(xr[cc + kx], wv, acc[cc][j]);
        }
      }
    }
  }

#pragma unroll
  for (int cc = 0; cc < 4; cc++) {
    short8v hv;
#pragma unroll
    for (int j = 0; j < 8; j++) hv[j] = (short)f2bf(lrelu(acc[cc][j]));
    *(short8v*)(h1 + (((size_t)b*516 + ty0 + y + 2)*516 + tx0 + x0 + cc + 2)*8) = hv;
  }
}

// ---------------------------------------------------------------------------
// Implicit-GEMM MFMA conv over PADDED NHWC input (no bounds checks).
// Writes padded output interior (pre-BN, +bias) and per-block BN partials.
// ---------------------------------------------------------------------------
template <int IC, int OC, int KSZ, int S, int P, int CPR, int NCH,
          int IPH, int IPW, int OWL, int OPH, int OPW,
          int WM, int WN, int WVM, int WVN, bool PERS>
__global__ __launch_bounds__(WVM*WVN*64) void conv_mfma(
    const u16* __restrict__ in, const u16* __restrict__ wmfma,
    const float* __restrict__ bias, u16* __restrict__ out,
    float2* __restrict__ part2) {
  constexpr int OW = 1 << OWL;
  constexpr int PADOFF = 2 - P;
  const int tid = threadIdx.x, lane = tid & 63;
  const int w = tid >> 6, wm = w % WVM, wn = w / WVM;
  const int l15 = lane & 15, sub = lane >> 4;
  const int b = blockIdx.z;
  const int px0 = blockIdx.x * (16*WM*WVM) + wm * (16*WM);
  const int oc0 = blockIdx.y * (16*WN*WVN) + wn * (16*WN);

  int oyf[WM], oxb[WM], ixb[WM];
#pragma unroll
  for (int f = 0; f < WM; f++) {
    int p = px0 + f*16;
    oyf[f] = p >> OWL;
    oxb[f] = p & (OW-1);
    ixb[f] = S*(oxb[f] + l15) + PADOFF;
  }
  const u16* inb = in + (size_t)b*IPH*IPW*IC;
  const u16* wbase = wmfma + (PERS ? (size_t)b*NCH*OC*32 : (size_t)0);

  float4v acc[WM][WN];
#pragma unroll
  for (int f = 0; f < WM; f++)
#pragma unroll
    for (int n = 0; n < WN; n++) acc[f][n] = (float4v){0.f,0.f,0.f,0.f};

#pragma unroll
  for (int ky = 0; ky < KSZ; ky++) {
#pragma unroll
    for (int r = 0; r < CPR; r++) {
      const int c = ky*CPR + r;
      const int kk0 = r*32 + sub*8;
      const int kx = kk0 / IC;
      const int icoff = kk0 % IC;
      short8v B[WN];
#pragma unroll
      for (int n = 0; n < WN; n++)
        B[n] = *(const short8v*)(wbase + ((size_t)c*OC + oc0 + n*16 + l15)*32 + sub*8);
      short8v A[WM];
#pragma unroll
      for (int f = 0; f < WM; f++) {
        int iy = S*oyf[f] + ky + PADOFF;
        A[f] = *(const short8v*)(inb + ((size_t)iy*IPW + ixb[f] + kx)*IC + icoff);
      }
#pragma unroll
      for (int f = 0; f < WM; f++)
#pragma unroll
        for (int n = 0; n < WN; n++)
          acc[f][n] = __builtin_amdgcn_mfma_f32_16x16x32_bf16(A[f], B[n], acc[f][n], 0, 0, 0);
    }
  }

  // epilogue: +bias, store bf16 interior, accumulate BN partials
  float s[WN], q[WN];
#pragma unroll
  for (int n = 0; n < WN; n++) { s[n] = 0.f; q[n] = 0.f; }
#pragma unroll
  for (int f = 0; f < WM; f++) {
    const int oxs = oxb[f] + sub*4;
    const size_t rowb = ((size_t)b*OPH + oyf[f] + 2)*OPW;
#pragma unroll
    for (int n = 0; n < WN; n++) {
      int oc = oc0 + n*16 + l15;
      float bv = bias[oc];
#pragma unroll
      for (int rr = 0; rr < 4; rr++) {
        float v = acc[f][n][rr] + bv;
        out[(rowb + oxs + rr + 2)*OC + oc] = f2bf(v);
        s[n] += v; q[n] += v*v;
      }
    }
  }
#pragma unroll
  for (int n = 0; n < WN; n++) {
    s[n] += __shfl_xor(s[n], 16); s[n] += __shfl_xor(s[n], 32);
    q[n] += __shfl_xor(q[n], 16); q[n] += __shfl_xor(q[n], 32);
  }
  __shared__ float sred[WVM*WVN][WN][16][2];
  if (sub == 0) {
#pragma unroll
    for (int n = 0; n < WN; n++) { sred[w][n][l15][0] = s[n]; sred[w][n][l15][1] = q[n]; }
  }
  __syncthreads();
  const int NBp = gridDim.x * gridDim.z;
  const int pb = blockIdx.z * gridDim.x + blockIdx.x;
  const int tot = WVN*WN*16;
  if (tid < tot) {
    int c16 = tid & 15, n = (tid >> 4) % WN, wn2 = tid / (16*WN);
    float S_ = 0.f, Q_ = 0.f;
    for (int wm2 = 0; wm2 < WVM; wm2++) {
      S_ += sred[wn2*WVM + wm2][n][c16][0];
      Q_ += sred[wn2*WVM + wm2][n][c16][1];
    }
    int c = blockIdx.y*(16*WN*WVN) + wn2*(16*WN) + n*16 + c16;
    part2[(size_t)c*NBp + pb] = make_float2(S_, Q_);
  }
}

// ---------------------------------------------------------------------------
// BN stage2: reduce per-block partials -> (scale, shift)
// ---------------------------------------------------------------------------
__global__ void bn_stage2(const float2* __restrict__ part2, const float* __restrict__ g,
                          const float* __restrict__ bb, float* __restrict__ stats,
                          int NBp, float invN) {
  int c = blockIdx.x;
  float s = 0.f, q = 0.f;
  for (int i = threadIdx.x; i < NBp; i += 64) {
    float2 p = part2[(size_t)c*NBp + i];
    s += p.x; q += p.y;
  }
  for (int o = 32; o > 0; o >>= 1) { s += __shfl_down(s, o); q += __shfl_down(q, o); }
  if (threadIdx.x == 0) {
    float m = s * invN;
    float var = q * invN - m*m;
    float sc = g[c] * rsqrtf(var + BN_EPS);
    stats[2*c] = sc;
    stats[2*c+1] = bb[c] - m*sc;
  }
}

// bn finalize in place over PADDED buffer: interior -> affine+lrelu, pads -> 0
template <int C, int PH, int PW, int HH, int WW>
__global__ __launch_bounds__(256) void bn_fin(u16* __restrict__ y, const float* __restrict__ stats,
                                              int total8) {
  int i = blockIdx.x*256 + threadIdx.x;
  if (i >= total8) return;
  size_t e = (size_t)i*8;
  int c0 = (int)(e & (C-1));
  int px = (int)(e / C);
  int xx = px % PW;
  int yy = (px / PW) % PH;
  bool interior = (yy >= 2) & (yy < 2+HH) & (xx >= 2) & (xx < 2+WW);
  short8v u = *(short8v*)(y + e);
  short8v o;
#pragma unroll
  for (int j = 0; j < 8; j++) {
    float v = bf2f((u16)u[j]) * stats[2*(c0+j)] + stats[2*(c0+j)+1];
    o[j] = interior ? (short)f2bf(lrelu(v)) : (short)0;
  }
  *(short8v*)(y + e) = o;
}

// final: lrelu(bn(y6pad interior)) NHWC bf16 -> NCHW fp32 d_out
__global__ __launch_bounds__(256) void out_k(const u16* __restrict__ y6,
                                             const float* __restrict__ stats,
                                             float* __restrict__ out) {
  int i = blockIdx.x*256 + threadIdx.x;
  if (i >= 131072) return;
  size_t e = (size_t)i*4;
  int c0 = (int)(e & 127);
  int px = (int)(e >> 7);
  int loc = px & 255, b = px >> 8;
  int y = loc >> 4, x = loc & 15;
  const u16* src = y6 + (((size_t)b*20 + y + 2)*20 + x + 2)*128 + c0;
  ushort4 u = *(const ushort4*)src;
  float vv[4] = {bf2f(u.x), bf2f(u.y), bf2f(u.z), bf2f(u.w)};
#pragma unroll
  for (int j = 0; j < 4; j++) {
    int c = c0 + j;
    float v = vv[j] * stats[2*c] + stats[2*c+1];
    out[(((size_t)b*128 + c) << 8) + loc] = lrelu(v);
  }
}

// ---------------------------------------------------------------------------
extern "C" void kernel_launch(void* const* d_in, const int* in_sizes, int n_in,
                              void* d_out, int out_size, void* d_ws, size_t ws_size,
                              hipStream_t stream) {
  const float* x    = (const float*)d_in[0];
  const float* cw   = (const float*)d_in[1];
  const float* w11  = (const float*)d_in[2];
  const float* b11  = (const float*)d_in[3];
  const float* w12  = (const float*)d_in[4];
  const float* b12  = (const float*)d_in[5];
  const float* bn1g = (const float*)d_in[6];
  const float* bn1b = (const float*)d_in[7];
  const float* c2w[4] = {(const float*)d_in[8], (const float*)d_in[12],
                         (const float*)d_in[16], (const float*)d_in[20]};
  const float* c2b[4] = {(const float*)d_in[9], (const float*)d_in[13],
                         (const float*)d_in[17], (const float*)d_in[21]};
  const float* bng[4] = {(const float*)d_in[10], (const float*)d_in[14],
                         (const float*)d_in[18], (const float*)d_in[22]};
  const float* bnb[4] = {(const float*)d_in[11], (const float*)d_in[15],
                         (const float*)d_in[19], (const float*)d_in[23]};

  char* ws = (char*)d_ws;
  // Region A [0, 68.16MB): h1pad during L1/L2; then y3..y6 pads + shared weights.
  u16* h1   = (u16*)(ws);                          // 16x516x516x8  = 68,158,464 B
  u16* y3   = (u16*)(ws);                          // 16x132x132x32 = 17,842,176
  u16* y4   = (u16*)(ws + 17842176);               // 16x68x68x64   =  9,469,952
  u16* y5   = (u16*)(ws + 27312128);               // 16x36x36x128  =  5,308,416
  u16* y6   = (u16*)(ws + 32620544);               // 16x20x20x128  =  1,638,400
  u16* wS1  = (u16*)(ws + 34258944);               // 30,720
  u16* wS2  = (u16*)(ws + 34289664);               // 102,400
  u16* wS3  = (u16*)(ws + 34392064);               // 147,456
  u16* wS4  = (u16*)(ws + 34539520);               // 294,912 -> ends 34,834,432
  // Region B [68.16MB, ...): xpad planar during L1; then yT2pad.
  u16* xpad = (u16*)(ws + 68158464);               // 3x16x516x520x2 = 25,758,720
  u16* yT2  = (u16*)(ws + 68158464);               // 16x260x260x16  = 34,611,200 -> ends 102,769,664
  // Tail: L2 meta weights + bias + partials + stats + wl1f
  u16* wl2m = (u16*)(ws + 102769664);              // 163,840
  float* bl2    = (float*)(ws + 102933504);        // 64
  float2* part2 = (float2*)(ws + 102933568);       // <= 524,288
  float* stats2 = (float*)(ws + 103457856);        // 16*2
  float* stats3 = stats2 + 32;                     // 32*2
  float* stats4 = stats3 + 64;                     // 64*2
  float* stats5 = stats4 + 128;                    // 128*2
  float* stats6 = stats5 + 256;                    // 128*2
  float* wl1f   = (float*)(ws + 103460800);        // 16*600*4 = 38,400

  prep_l2m<<<320, 256, 0, stream>>>(w12, b12, w11, cw, wl2m, bl2, wl1f);
  zero_xpad<<<1158, 256, 0, stream>>>(xpad);
  convert_x<<<6144, 256, 0, stream>>>(x, xpad);

  // L1: 3->8 k5 s1 -> h1pad interior (post-lrelu); zero pad frame
  conv_l1<<<dim3(256, 1, 16), 256, 0, stream>>>(xpad, wl1f, b11, h1);
  zero_h1pad<<<257, 256, 0, stream>>>(h1);

  // L2: 8->16 k5 s2, per-sample weights -> yT2pad (pre-BN) + partials
  conv_mfma<8,16,5,2,2, 2,10, 516,516, 8, 260,260, 4,1,4,1, true>
      <<<dim3(256,1,16), 256, 0, stream>>>(h1, wl2m, bl2, yT2, part2);

  // shared-weight packs (into region A — after L2 in stream order)
  prep_wall<<<1124, 256, 0, stream>>>(c2w[0], c2w[1], c2w[2], c2w[3], wS1, wS2, wS3, wS4);

  bn_stage2<<<16, 64, 0, stream>>>(part2, bn1g, bn1b, stats2, 4096, 1.f/1048576.f);
  bn_fin<16,260,260,256,256><<<8450, 256, 0, stream>>>(yT2, stats2, 2163200);

  // S1: 16->32 k5 s2 -> y3pad
  conv_mfma<16,32,5,2,2, 3,15, 260,260, 7, 132,132, 2,2,4,1, false>
      <<<dim3(128,1,16), 256, 0, stream>>>(yT2, wS1, c2b[0], y3, part2);
  bn_stage2<<<32, 64, 0, stream>>>(part2, bng[0], bnb[0], stats3, 2048, 1.f/262144.f);
  bn_fin<32,132,132,128,128><<<4356, 256, 0, stream>>>(y3, stats3, 1115136);

  // S2: 32->64 k5 s2 -> y4pad
  conv_mfma<32,64,5,2,2, 5,25, 132,132, 6, 68,68, 2,2,2,2, false>
      <<<dim3(64,1,16), 256, 0, stream>>>(y3, wS2, c2b[1], y4, part2);
  bn_stage2<<<64, 64, 0, stream>>>(part2, bng[1], bnb[1], stats4, 1024, 1.f/65536.f);
  bn_fin<64,68,68,64,64><<<2312, 256, 0, stream>>>(y4, stats4, 591872);

  // S3: 64->128 k3 s2 -> y5pad
  conv_mfma<64,128,3,2,1, 6,18, 68,68, 5, 36,36, 2,2,2,2, false>
      <<<dim3(16,2,16), 256, 0, stream>>>(y4, wS3, c2b[2], y5, part2);
  bn_stage2<<<128, 64, 0, stream>>>(part2, bng[2], bnb[2], stats5, 256, 1.f/16384.f);
  bn_fin<128,36,36,32,32><<<1296, 256, 0, stream>>>(y5, stats5, 331776);

  // S4: 128->128 k3 s2 -> y6pad (pre-BN)
  conv_mfma<128,128,3,2,1, 12,36, 36,36, 4, 20,20, 2,2,1,2, false>
      <<<dim3(8,2,16), 128, 0, stream>>>(y5, wS4, c2b[3], y6, part2);
  bn_stage2<<<128, 64, 0, stream>>>(part2, bng[3], bnb[3], stats6, 128, 1.f/4096.f);

  out_k<<<512, 256, 0, stream>>>(y6, stats6, (float*)d_out);
}

// Round 6
// 277.239 us; speedup vs baseline: 1.1848x; 1.1198x over previous
//
#include <hip/hip_runtime.h>

// CNN encoder round 6 (= round 5 + two fixes):
//  - FIX: wS1..wS4 moved OUT of h1pad's byte range into the tail (they were
//    being clobbered by conv_l1's h1 writes since prep_all now runs first).
//  - FIX: prep_all else-chain so i<16 doesn't take the wl2m branch (negative j).
//  - conv_l1 via MFMA: x staged to LDS as NHWC C=4 bf16; K-chunk (ky) =
//    kx0..7 x ic0..3 -> A-frag is a raw contiguous LDS load; weights packed
//    [b][ky][oc16][32] with zeros at kx>=5, ic=3, oc>=8.

typedef __attribute__((ext_vector_type(8))) short short8v;
typedef __attribute__((ext_vector_type(4))) float float4v;
typedef unsigned short u16;

#define LRELU_NEG 0.2f
#define BN_EPS 1e-5f

__device__ __forceinline__ float bf2f(u16 u){ union{unsigned i; float f;} v; v.i=(unsigned)u<<16; return v.f; }
__device__ __forceinline__ u16 f2bf(float f){ unsigned x=__float_as_uint(f); x += 0x7FFFu + ((x>>16)&1u); return (u16)(x>>16); }
__device__ __forceinline__ float lrelu(float v){ return v<0.f? LRELU_NEG*v : v; }

// ---------------------------------------------------------------------------
// prep_all: all weight packing + h1 pad zeroing + bl2, one kernel.
// ---------------------------------------------------------------------------
__device__ __forceinline__ void packw(int i, const float* __restrict__ w, u16* __restrict__ dst,
                                      int IC, int OC, int KSZ, int CPR) {
  int kq = i & 31, oc = (i>>5) % OC, c = i/(OC*32);
  int ky = c / CPR, r = c % CPR;
  int kk = r*32 + kq; int kx = kk / IC, ic = kk % IC;
  float v = (kx < KSZ) ? w[(((size_t)oc*IC + ic)*KSZ + ky)*KSZ + kx] : 0.f;
  dst[i] = f2bf(v);
}

__global__ __launch_bounds__(256) void prep_all(
    const float* __restrict__ w11, const float* __restrict__ w12,
    const float* __restrict__ b12, const float* __restrict__ cw,
    const float* __restrict__ wc1, const float* __restrict__ wc2,
    const float* __restrict__ wc3, const float* __restrict__ wc4,
    u16* __restrict__ wl1m, u16* __restrict__ wl2m, float* __restrict__ bl2,
    u16* __restrict__ d1, u16* __restrict__ d2, u16* __restrict__ d3, u16* __restrict__ d4,
    u16* __restrict__ h1) {
  int i = blockIdx.x*256 + threadIdx.x;
  if (i < 16) {
    bl2[i] = (i<8)? b12[i] : 0.f;
  } else if (i < 40976) {                        // wl1m [b][ky][oc16][kk32]
    int j = i - 16;
    int b = j / 2560, r = j % 2560;
    int ky = r >> 9, r2 = r & 511;
    int oc = r2 >> 5, kk = r2 & 31;
    int kx = kk >> 2, ic = kk & 3;
    float v = 0.f;
    if (ic < 3 && kx < 5 && oc < 8)
      v = (oc < 4) ? w11[((oc*3+ic)*5+ky)*5+kx]
                   : cw[b*1900 + (oc-4)*75 + ic*25 + ky*5 + kx];
    wl1m[j] = f2bf(v);
  } else if (i < 122896) {                       // wl2m [b][c10][oc16][kq32]
    int j = i - 40976;
    int kq = j & 31, oc = (j>>5) & 15, c = (j>>9) % 10, b = j / 5120;
    int ky = c >> 1, r = c & 1;
    int kk = r*32 + kq; int kx = kk >> 3, ic = kk & 7;
    float v = 0.f;
    if (kx < 5)
      v = (oc < 8) ? w12[((oc*8+ic)*5+ky)*5+kx]
                   : cw[b*1900 + 300 + ((oc-8)*8+ic)*25 + ky*5 + kx];
    wl2m[j] = f2bf(v);
  } else if (i < 188688) {                       // zero h1pad frame
    int j = i - 122896;
    int b = j / 4112, p = j % 4112;
    int y, xx;
    if (p < 2064) { int r = p/516; y = (r<2)? r : 512+r; xx = p%516; }
    else          { int q = p-2064; int cidx = q&3; xx = (cidx<2)? cidx : 512+cidx; y = 2 + (q>>2); }
    short8v z = {0,0,0,0,0,0,0,0};
    *(short8v*)(h1 + (((size_t)b*516 + y)*516 + xx)*8) = z;
  } else if (i < 476432) {                       // shared-weight packs
    int j = i - 188688;
    if (j < 15360) packw(j, wc1, d1, 16, 32, 5, 3);
    else if (j < 66560) packw(j-15360, wc2, d2, 32, 64, 5, 5);
    else if (j < 140288) packw(j-66560, wc3, d3, 64, 128, 3, 6);
    else packw(j-140288, wc4, d4, 128, 128, 3, 12);
  }
}

// ---------------------------------------------------------------------------
// L1 via MFMA: 3->8 k5 s1 p2, per-sample weights.
// Block: 64 px x 8 rows of h1; 4 waves, wave w owns px strip w*16.
// LDS x-tile [12 rows][72 cols][4 ch] bf16 (ch3 = 0), staged from x f32.
// A-frag (chunk ky): 8 contiguous bf16 at ((ly+ky)*72 + strip+l15)*4 + sub*8.
// ---------------------------------------------------------------------------
__global__ __launch_bounds__(256) void conv_l1(const float* __restrict__ x,
    const u16* __restrict__ wl1m, const float* __restrict__ b11,
    u16* __restrict__ h1) {
  __shared__ u16 sx[12*72*4];
  const int tid = threadIdx.x, b = blockIdx.z;
  const int x0 = (blockIdx.x & 7) * 64;
  const int r0 = (blockIdx.x >> 3) * 8;

  for (int e = tid; e < 864; e += 256) {
    int row = e / 72, col = e % 72;
    int gy = r0 + row - 2, gx = x0 + col - 2;
    float v0 = 0.f, v1 = 0.f, v2 = 0.f;
    if (gy >= 0 && gy < 512 && gx >= 0 && gx < 512) {
      size_t base = ((size_t)b*3*512 + gy)*512 + gx;
      v0 = x[base]; v1 = x[base + 262144]; v2 = x[base + 524288];
    }
    ushort4 pk = {f2bf(v0), f2bf(v1), f2bf(v2), 0};
    *(ushort4*)(sx + e*4) = pk;
  }
  __syncthreads();

  const int lane = tid & 63, w = tid >> 6;
  const int l15 = lane & 15, sub = lane >> 4;

  short8v Bf[5];
  const u16* wb = wl1m + (size_t)b*2560;
#pragma unroll
  for (int c = 0; c < 5; c++)
    Bf[c] = *(const short8v*)(wb + (c*16 + l15)*32 + sub*8);
  const float bv = (l15 < 4) ? b11[l15] : 0.f;

  const int colb = w*16 + l15;
#pragma unroll 2
  for (int ly = 0; ly < 8; ly++) {
    float4v acc = {0.f, 0.f, 0.f, 0.f};
#pragma unroll
    for (int c = 0; c < 5; c++) {
      const u16* ap = sx + (((ly + c)*72 + colb) << 2) + sub*8;
      union { unsigned long long q[2]; short8v v; } ua;
      ua.q[0] = *(const unsigned long long*)(ap);
      ua.q[1] = *(const unsigned long long*)(ap + 4);
      acc = __builtin_amdgcn_mfma_f32_16x16x32_bf16(ua.v, Bf[c], acc, 0, 0, 0);
    }
    if (l15 < 8) {
      size_t rb = (((size_t)b*516 + r0 + ly + 2)*516 + x0 + w*16 + sub*4 + 2)*8 + l15;
#pragma unroll
      for (int r = 0; r < 4; r++)
        h1[rb + r*8] = f2bf(lrelu(acc[r] + bv));
    }
  }
}

// ---------------------------------------------------------------------------
// Implicit-GEMM MFMA conv over PADDED NHWC input (no bounds checks).
// Writes padded output interior (pre-BN, +bias) and per-block BN partials.
// ---------------------------------------------------------------------------
template <int IC, int OC, int KSZ, int S, int P, int CPR, int NCH,
          int IPH, int IPW, int OWL, int OPH, int OPW,
          int WM, int WN, int WVM, int WVN, bool PERS>
__global__ __launch_bounds__(WVM*WVN*64) void conv_mfma(
    const u16* __restrict__ in, const u16* __restrict__ wmfma,
    const float* __restrict__ bias, u16* __restrict__ out,
    float2* __restrict__ part2) {
  constexpr int OW = 1 << OWL;
  constexpr int PADOFF = 2 - P;
  const int tid = threadIdx.x, lane = tid & 63;
  const int w = tid >> 6, wm = w % WVM, wn = w / WVM;
  const int l15 = lane & 15, sub = lane >> 4;
  const int b = blockIdx.z;
  const int px0 = blockIdx.x * (16*WM*WVM) + wm * (16*WM);
  const int oc0 = blockIdx.y * (16*WN*WVN) + wn * (16*WN);

  int oyf[WM], oxb[WM], ixb[WM];
#pragma unroll
  for (int f = 0; f < WM; f++) {
    int p = px0 + f*16;
    oyf[f] = p >> OWL;
    oxb[f] = p & (OW-1);
    ixb[f] = S*(oxb[f] + l15) + PADOFF;
  }
  const u16* inb = in + (size_t)b*IPH*IPW*IC;
  const u16* wbase = wmfma + (PERS ? (size_t)b*NCH*OC*32 : (size_t)0);

  float4v acc[WM][WN];
#pragma unroll
  for (int f = 0; f < WM; f++)
#pragma unroll
    for (int n = 0; n < WN; n++) acc[f][n] = (float4v){0.f,0.f,0.f,0.f};

#pragma unroll
  for (int ky = 0; ky < KSZ; ky++) {
#pragma unroll
    for (int r = 0; r < CPR; r++) {
      const int c = ky*CPR + r;
      const int kk0 = r*32 + sub*8;
      const int kx = kk0 / IC;
      const int icoff = kk0 % IC;
      short8v B[WN];
#pragma unroll
      for (int n = 0; n < WN; n++)
        B[n] = *(const short8v*)(wbase + ((size_t)c*OC + oc0 + n*16 + l15)*32 + sub*8);
      short8v A[WM];
#pragma unroll
      for (int f = 0; f < WM; f++) {
        int iy = S*oyf[f] + ky + PADOFF;
        A[f] = *(const short8v*)(inb + ((size_t)iy*IPW + ixb[f] + kx)*IC + icoff);
      }
#pragma unroll
      for (int f = 0; f < WM; f++)
#pragma unroll
        for (int n = 0; n < WN; n++)
          acc[f][n] = __builtin_amdgcn_mfma_f32_16x16x32_bf16(A[f], B[n], acc[f][n], 0, 0, 0);
    }
  }

  // epilogue: +bias, store bf16 interior, accumulate BN partials
  float s[WN], q[WN];
#pragma unroll
  for (int n = 0; n < WN; n++) { s[n] = 0.f; q[n] = 0.f; }
#pragma unroll
  for (int f = 0; f < WM; f++) {
    const int oxs = oxb[f] + sub*4;
    const size_t rowb = ((size_t)b*OPH + oyf[f] + 2)*OPW;
#pragma unroll
    for (int n = 0; n < WN; n++) {
      int oc = oc0 + n*16 + l15;
      float bv = bias[oc];
#pragma unroll
      for (int rr = 0; rr < 4; rr++) {
        float v = acc[f][n][rr] + bv;
        out[(rowb + oxs + rr + 2)*OC + oc] = f2bf(v);
        s[n] += v; q[n] += v*v;
      }
    }
  }
#pragma unroll
  for (int n = 0; n < WN; n++) {
    s[n] += __shfl_xor(s[n], 16); s[n] += __shfl_xor(s[n], 32);
    q[n] += __shfl_xor(q[n], 16); q[n] += __shfl_xor(q[n], 32);
  }
  __shared__ float sred[WVM*WVN][WN][16][2];
  if (sub == 0) {
#pragma unroll
    for (int n = 0; n < WN; n++) { sred[w][n][l15][0] = s[n]; sred[w][n][l15][1] = q[n]; }
  }
  __syncthreads();
  const int NBp = gridDim.x * gridDim.z;
  const int pb = blockIdx.z * gridDim.x + blockIdx.x;
  const int tot = WVN*WN*16;
  if (tid < tot) {
    int c16 = tid & 15, n = (tid >> 4) % WN, wn2 = tid / (16*WN);
    float S_ = 0.f, Q_ = 0.f;
    for (int wm2 = 0; wm2 < WVM; wm2++) {
      S_ += sred[wn2*WVM + wm2][n][c16][0];
      Q_ += sred[wn2*WVM + wm2][n][c16][1];
    }
    int c = blockIdx.y*(16*WN*WVN) + wn2*(16*WN) + n*16 + c16;
    part2[(size_t)c*NBp + pb] = make_float2(S_, Q_);
  }
}

// ---------------------------------------------------------------------------
// BN stage2: reduce per-block partials -> (scale, shift)
// ---------------------------------------------------------------------------
__global__ void bn_stage2(const float2* __restrict__ part2, const float* __restrict__ g,
                          const float* __restrict__ bb, float* __restrict__ stats,
                          int NBp, float invN) {
  int c = blockIdx.x;
  float s = 0.f, q = 0.f;
  for (int i = threadIdx.x; i < NBp; i += 64) {
    float2 p = part2[(size_t)c*NBp + i];
    s += p.x; q += p.y;
  }
  for (int o = 32; o > 0; o >>= 1) { s += __shfl_down(s, o); q += __shfl_down(q, o); }
  if (threadIdx.x == 0) {
    float m = s * invN;
    float var = q * invN - m*m;
    float sc = g[c] * rsqrtf(var + BN_EPS);
    stats[2*c] = sc;
    stats[2*c+1] = bb[c] - m*sc;
  }
}

// bn finalize in place over PADDED buffer: interior -> affine+lrelu, pads -> 0
template <int C, int PH, int PW, int HH, int WW>
__global__ __launch_bounds__(256) void bn_fin(u16* __restrict__ y, const float* __restrict__ stats,
                                              int total8) {
  int i = blockIdx.x*256 + threadIdx.x;
  if (i >= total8) return;
  size_t e = (size_t)i*8;
  int c0 = (int)(e & (C-1));
  int px = (int)(e / C);
  int xx = px % PW;
  int yy = (px / PW) % PH;
  bool interior = (yy >= 2) & (yy < 2+HH) & (xx >= 2) & (xx < 2+WW);
  short8v u = *(short8v*)(y + e);
  short8v o;
#pragma unroll
  for (int j = 0; j < 8; j++) {
    float v = bf2f((u16)u[j]) * stats[2*(c0+j)] + stats[2*(c0+j)+1];
    o[j] = interior ? (short)f2bf(lrelu(v)) : (short)0;
  }
  *(short8v*)(y + e) = o;
}

// final: lrelu(bn(y6pad interior)) NHWC bf16 -> NCHW fp32 d_out
__global__ __launch_bounds__(256) void out_k(const u16* __restrict__ y6,
                                             const float* __restrict__ stats,
                                             float* __restrict__ out) {
  int i = blockIdx.x*256 + threadIdx.x;
  if (i >= 131072) return;
  size_t e = (size_t)i*4;
  int c0 = (int)(e & 127);
  int px = (int)(e >> 7);
  int loc = px & 255, b = px >> 8;
  int y = loc >> 4, x = loc & 15;
  const u16* src = y6 + (((size_t)b*20 + y + 2)*20 + x + 2)*128 + c0;
  ushort4 u = *(const ushort4*)src;
  float vv[4] = {bf2f(u.x), bf2f(u.y), bf2f(u.z), bf2f(u.w)};
#pragma unroll
  for (int j = 0; j < 4; j++) {
    int c = c0 + j;
    float v = vv[j] * stats[2*c] + stats[2*c+1];
    out[(((size_t)b*128 + c) << 8) + loc] = lrelu(v);
  }
}

// ---------------------------------------------------------------------------
extern "C" void kernel_launch(void* const* d_in, const int* in_sizes, int n_in,
                              void* d_out, int out_size, void* d_ws, size_t ws_size,
                              hipStream_t stream) {
  const float* x    = (const float*)d_in[0];
  const float* cw   = (const float*)d_in[1];
  const float* w11  = (const float*)d_in[2];
  const float* b11  = (const float*)d_in[3];
  const float* w12  = (const float*)d_in[4];
  const float* b12  = (const float*)d_in[5];
  const float* bn1g = (const float*)d_in[6];
  const float* bn1b = (const float*)d_in[7];
  const float* c2w[4] = {(const float*)d_in[8], (const float*)d_in[12],
                         (const float*)d_in[16], (const float*)d_in[20]};
  const float* c2b[4] = {(const float*)d_in[9], (const float*)d_in[13],
                         (const float*)d_in[17], (const float*)d_in[21]};
  const float* bng[4] = {(const float*)d_in[10], (const float*)d_in[14],
                         (const float*)d_in[18], (const float*)d_in[22]};
  const float* bnb[4] = {(const float*)d_in[11], (const float*)d_in[15],
                         (const float*)d_in[19], (const float*)d_in[23]};

  char* ws = (char*)d_ws;
  // Region A [0, 68.16MB): h1pad during L1/L2; then y3..y6 pads (S1..S4 phase).
  u16* h1   = (u16*)(ws);                          // 16x516x516x8  = 68,158,464 B
  u16* y3   = (u16*)(ws);                          // 16x132x132x32 = 17,842,176
  u16* y4   = (u16*)(ws + 17842176);               // 16x68x68x64   =  9,469,952
  u16* y5   = (u16*)(ws + 27312128);               // 16x36x36x128  =  5,308,416
  u16* y6   = (u16*)(ws + 32620544);               // 16x20x20x128  =  1,638,400
  // Region B [68.16MB, 102.77MB): yT2pad.
  u16* yT2  = (u16*)(ws + 68158464);               // 16x260x260x16 = 34,611,200
  // Tail [102.77MB, 104.12MB): everything with whole-run lifetime.
  u16* wl2m = (u16*)(ws + 102769664);              // 163,840
  float* bl2    = (float*)(ws + 102933504);        // 64
  float2* part2 = (float2*)(ws + 102933568);       // 524,288
  float* stats2 = (float*)(ws + 103457856);        // stats total 2,944
  float* stats3 = stats2 + 32;
  float* stats4 = stats3 + 64;
  float* stats5 = stats4 + 128;
  float* stats6 = stats5 + 256;
  u16* wl1m = (u16*)(ws + 103460800);              // 81,920 -> ends 103,542,720
  u16* wS1  = (u16*)(ws + 103542720);              // 30,720
  u16* wS2  = (u16*)(ws + 103573440);              // 102,400
  u16* wS3  = (u16*)(ws + 103675840);              // 147,456
  u16* wS4  = (u16*)(ws + 103823296);              // 294,912 -> ends 104,118,208

  prep_all<<<1862, 256, 0, stream>>>(w11, w12, b12, cw,
                                     c2w[0], c2w[1], c2w[2], c2w[3],
                                     wl1m, wl2m, bl2, wS1, wS2, wS3, wS4, h1);

  // L1: 3->8 k5 s1 -> h1pad interior (post-lrelu), MFMA
  conv_l1<<<dim3(512, 1, 16), 256, 0, stream>>>(x, wl1m, b11, h1);

  // L2: 8->16 k5 s2, per-sample weights -> yT2pad (pre-BN) + partials
  conv_mfma<8,16,5,2,2, 2,10, 516,516, 8, 260,260, 4,1,4,1, true>
      <<<dim3(256,1,16), 256, 0, stream>>>(h1, wl2m, bl2, yT2, part2);

  bn_stage2<<<16, 64, 0, stream>>>(part2, bn1g, bn1b, stats2, 4096, 1.f/1048576.f);
  bn_fin<16,260,260,256,256><<<8450, 256, 0, stream>>>(yT2, stats2, 2163200);

  // S1: 16->32 k5 s2 -> y3pad
  conv_mfma<16,32,5,2,2, 3,15, 260,260, 7, 132,132, 2,2,4,1, false>
      <<<dim3(128,1,16), 256, 0, stream>>>(yT2, wS1, c2b[0], y3, part2);
  bn_stage2<<<32, 64, 0, stream>>>(part2, bng[0], bnb[0], stats3, 2048, 1.f/262144.f);
  bn_fin<32,132,132,128,128><<<4356, 256, 0, stream>>>(y3, stats3, 1115136);

  // S2: 32->64 k5 s2 -> y4pad
  conv_mfma<32,64,5,2,2, 5,25, 132,132, 6, 68,68, 2,2,2,2, false>
      <<<dim3(64,1,16), 256, 0, stream>>>(y3, wS2, c2b[1], y4, part2);
  bn_stage2<<<64, 64, 0, stream>>>(part2, bng[1], bnb[1], stats4, 1024, 1.f/65536.f);
  bn_fin<64,68,68,64,64><<<2312, 256, 0, stream>>>(y4, stats4, 591872);

  // S3: 64->128 k3 s2 -> y5pad
  conv_mfma<64,128,3,2,1, 6,18, 68,68, 5, 36,36, 2,2,2,2, false>
      <<<dim3(16,2,16), 256, 0, stream>>>(y4, wS3, c2b[2], y5, part2);
  bn_stage2<<<128, 64, 0, stream>>>(part2, bng[2], bnb[2], stats5, 256, 1.f/16384.f);
  bn_fin<128,36,36,32,32><<<1296, 256, 0, stream>>>(y5, stats5, 331776);

  // S4: 128->128 k3 s2 -> y6pad (pre-BN)
  conv_mfma<128,128,3,2,1, 12,36, 36,36, 4, 20,20, 2,2,1,2, false>
      <<<dim3(8,2,16), 128, 0, stream>>>(y5, wS4, c2b[3], y6, part2);
  bn_stage2<<<128, 64, 0, stream>>>(part2, bng[3], bnb[3], stats6, 128, 1.f/4096.f);

  out_k<<<512, 256, 0, stream>>>(y6, stats6, (float*)d_out);
}

// Round 7
// 271.705 us; speedup vs baseline: 1.2089x; 1.0204x over previous
//
#include <hip/hip_runtime.h>

// CNN encoder round 7:
//  - conv_l1: operand-swapped MFMA (W first -> D rows=weights, cols=px), so each
//    lane stores 4 consecutive channels of one px as one 8B store (vs 32 scalar
//    u16 stores); dual-row weight packing (rows 0..7 = ky=c, 8..15 = ky=c-1)
//    -> 24 MFMA/wave vs 40, all lanes productive; interior staging fast-path.
//  - everything else unchanged from round 6.

typedef __attribute__((ext_vector_type(8))) short short8v;
typedef __attribute__((ext_vector_type(4))) float float4v;
typedef __attribute__((ext_vector_type(4))) unsigned short ushort4v;
typedef unsigned short u16;

#define LRELU_NEG 0.2f
#define BN_EPS 1e-5f

__device__ __forceinline__ float bf2f(u16 u){ union{unsigned i; float f;} v; v.i=(unsigned)u<<16; return v.f; }
__device__ __forceinline__ u16 f2bf(float f){ unsigned x=__float_as_uint(f); x += 0x7FFFu + ((x>>16)&1u); return (u16)(x>>16); }
__device__ __forceinline__ float lrelu(float v){ return v<0.f? LRELU_NEG*v : v; }

// ---------------------------------------------------------------------------
// prep_all: all weight packing + h1 pad zeroing + bl2, one kernel.
// ---------------------------------------------------------------------------
__device__ __forceinline__ void packw(int i, const float* __restrict__ w, u16* __restrict__ dst,
                                      int IC, int OC, int KSZ, int CPR) {
  int kq = i & 31, oc = (i>>5) % OC, c = i/(OC*32);
  int ky = c / CPR, r = c % CPR;
  int kk = r*32 + kq; int kx = kk / IC, ic = kk % IC;
  float v = (kx < KSZ) ? w[(((size_t)oc*IC + ic)*KSZ + ky)*KSZ + kx] : 0.f;
  dst[i] = f2bf(v);
}

__global__ __launch_bounds__(256) void prep_all(
    const float* __restrict__ w11, const float* __restrict__ w12,
    const float* __restrict__ b12, const float* __restrict__ cw,
    const float* __restrict__ wc1, const float* __restrict__ wc2,
    const float* __restrict__ wc3, const float* __restrict__ wc4,
    u16* __restrict__ wl1d, u16* __restrict__ wl2m, float* __restrict__ bl2,
    u16* __restrict__ d1, u16* __restrict__ d2, u16* __restrict__ d3, u16* __restrict__ d4,
    u16* __restrict__ h1) {
  int i = blockIdx.x*256 + threadIdx.x;
  if (i < 16) {
    bl2[i] = (i<8)? b12[i] : 0.f;
  } else if (i < 49168) {                        // wl1d [b][c6][row16][k32]
    int j = i - 16;
    int b = j / 3072, r = j % 3072;
    int c = r >> 9, r2 = r & 511;
    int row = r2 >> 5, kk = r2 & 31;
    int kx = kk >> 2, ic = kk & 3;
    int grp = row >> 3, oc = row & 7;
    int ky = c - grp;
    float v = 0.f;
    if (ic < 3 && kx < 5 && ky >= 0 && ky < 5)
      v = (oc < 4) ? w11[((oc*3+ic)*5+ky)*5+kx]
                   : cw[b*1900 + (oc-4)*75 + ic*25 + ky*5 + kx];
    wl1d[j] = f2bf(v);
  } else if (i < 131088) {                       // wl2m [b][c10][oc16][kq32]
    int j = i - 49168;
    int kq = j & 31, oc = (j>>5) & 15, c = (j>>9) % 10, b = j / 5120;
    int ky = c >> 1, r = c & 1;
    int kk = r*32 + kq; int kx = kk >> 3, ic = kk & 7;
    float v = 0.f;
    if (kx < 5)
      v = (oc < 8) ? w12[((oc*8+ic)*5+ky)*5+kx]
                   : cw[b*1900 + 300 + ((oc-8)*8+ic)*25 + ky*5 + kx];
    wl2m[j] = f2bf(v);
  } else if (i < 196880) {                       // zero h1pad frame
    int j = i - 131088;
    int b = j / 4112, p = j % 4112;
    int y, xx;
    if (p < 2064) { int r = p/516; y = (r<2)? r : 512+r; xx = p%516; }
    else          { int q = p-2064; int cidx = q&3; xx = (cidx<2)? cidx : 512+cidx; y = 2 + (q>>2); }
    short8v z = {0,0,0,0,0,0,0,0};
    *(short8v*)(h1 + (((size_t)b*516 + y)*516 + xx)*8) = z;
  } else if (i < 484624) {                       // shared-weight packs
    int j = i - 196880;
    if (j < 15360) packw(j, wc1, d1, 16, 32, 5, 3);
    else if (j < 66560) packw(j-15360, wc2, d2, 32, 64, 5, 5);
    else if (j < 140288) packw(j-66560, wc3, d3, 64, 128, 3, 6);
    else packw(j-140288, wc4, d4, 128, 128, 3, 12);
  }
}

// ---------------------------------------------------------------------------
// L1 via MFMA (operand-swapped, dual-row): 3->8 k5 s1 p2, per-sample weights.
// Block: 64 px x 8 rows; 4 waves, wave w owns px strip w*16.
// LDS x-tile [12 rows][72 cols][4 ch] bf16 (ch3=0).
// Chunk c=0..5: W rows 0..7 = oc0..7 @ky=c, rows 8..15 = oc0..7 @ky=c-1
// (zeros out of range). mfma(W, X): D[row=sub*4+r][col=l15] ->
// out_row = 2p + (sub>>1), oc = (sub&1)*4 + r, px = l15. Store = 8B/lane.
// ---------------------------------------------------------------------------
__global__ __launch_bounds__(256) void conv_l1(const float* __restrict__ x,
    const u16* __restrict__ wl1d, const float* __restrict__ b11,
    u16* __restrict__ h1) {
  __shared__ u16 sx[12*72*4];
  const int tid = threadIdx.x, b = blockIdx.z;
  const int x0 = (blockIdx.x & 7) * 64;
  const int r0 = (blockIdx.x >> 3) * 8;

  const bool interior = (r0 >= 2) & (r0 <= 502) & (x0 >= 2) & (x0 <= 442);
  if (interior) {
    for (int e = tid; e < 864; e += 256) {
      int row = e / 72, col = e % 72;
      size_t base = ((size_t)b*3*512 + r0 + row - 2)*512 + x0 + col - 2;
      ushort4 pk = {f2bf(x[base]), f2bf(x[base + 262144]), f2bf(x[base + 524288]), 0};
      *(ushort4*)(sx + e*4) = pk;
    }
  } else {
    for (int e = tid; e < 864; e += 256) {
      int row = e / 72, col = e % 72;
      int gy = r0 + row - 2, gx = x0 + col - 2;
      float v0 = 0.f, v1 = 0.f, v2 = 0.f;
      if (gy >= 0 && gy < 512 && gx >= 0 && gx < 512) {
        size_t base = ((size_t)b*3*512 + gy)*512 + gx;
        v0 = x[base]; v1 = x[base + 262144]; v2 = x[base + 524288];
      }
      ushort4 pk = {f2bf(v0), f2bf(v1), f2bf(v2), 0};
      *(ushort4*)(sx + e*4) = pk;
    }
  }
  __syncthreads();

  const int lane = tid & 63, w = tid >> 6;
  const int l15 = lane & 15, sub = lane >> 4;

  short8v Wf[6];
  const u16* wb = wl1d + (size_t)b*3072;
#pragma unroll
  for (int c = 0; c < 6; c++)
    Wf[c] = *(const short8v*)(wb + (c*16 + l15)*32 + sub*8);

  float bvv[4];
#pragma unroll
  for (int r = 0; r < 4; r++) bvv[r] = (sub & 1) ? 0.f : b11[r];

  const int colb = w*16 + l15;
  const int oc0 = (sub & 1) * 4;
  const int rsel = sub >> 1;

#pragma unroll
  for (int p = 0; p < 4; p++) {
    float4v acc = {0.f, 0.f, 0.f, 0.f};
#pragma unroll
    for (int c = 0; c < 6; c++) {
      const u16* ap = sx + (((2*p + c)*72 + colb) << 2) + sub*8;
      union { unsigned long long q[2]; short8v v; } ua;
      ua.q[0] = *(const unsigned long long*)(ap);
      ua.q[1] = *(const unsigned long long*)(ap + 4);
      acc = __builtin_amdgcn_mfma_f32_16x16x32_bf16(Wf[c], ua.v, acc, 0, 0, 0);
    }
    ushort4v pk;
#pragma unroll
    for (int r = 0; r < 4; r++) pk[r] = f2bf(lrelu(acc[r] + bvv[r]));
    int outrow = r0 + 2*p + rsel;
    u16* dst = h1 + (((size_t)b*516 + outrow + 2)*516 + x0 + colb + 2)*8 + oc0;
    *(ushort4v*)dst = pk;
  }
}

// ---------------------------------------------------------------------------
// Implicit-GEMM MFMA conv over PADDED NHWC input (no bounds checks).
// Writes padded output interior (pre-BN, +bias) and per-block BN partials.
// ---------------------------------------------------------------------------
template <int IC, int OC, int KSZ, int S, int P, int CPR, int NCH,
          int IPH, int IPW, int OWL, int OPH, int OPW,
          int WM, int WN, int WVM, int WVN, bool PERS>
__global__ __launch_bounds__(WVM*WVN*64) void conv_mfma(
    const u16* __restrict__ in, const u16* __restrict__ wmfma,
    const float* __restrict__ bias, u16* __restrict__ out,
    float2* __restrict__ part2) {
  constexpr int OW = 1 << OWL;
  constexpr int PADOFF = 2 - P;
  const int tid = threadIdx.x, lane = tid & 63;
  const int w = tid >> 6, wm = w % WVM, wn = w / WVM;
  const int l15 = lane & 15, sub = lane >> 4;
  const int b = blockIdx.z;
  const int px0 = blockIdx.x * (16*WM*WVM) + wm * (16*WM);
  const int oc0 = blockIdx.y * (16*WN*WVN) + wn * (16*WN);

  int oyf[WM], oxb[WM], ixb[WM];
#pragma unroll
  for (int f = 0; f < WM; f++) {
    int p = px0 + f*16;
    oyf[f] = p >> OWL;
    oxb[f] = p & (OW-1);
    ixb[f] = S*(oxb[f] + l15) + PADOFF;
  }
  const u16* inb = in + (size_t)b*IPH*IPW*IC;
  const u16* wbase = wmfma + (PERS ? (size_t)b*NCH*OC*32 : (size_t)0);

  float4v acc[WM][WN];
#pragma unroll
  for (int f = 0; f < WM; f++)
#pragma unroll
    for (int n = 0; n < WN; n++) acc[f][n] = (float4v){0.f,0.f,0.f,0.f};

#pragma unroll
  for (int ky = 0; ky < KSZ; ky++) {
#pragma unroll
    for (int r = 0; r < CPR; r++) {
      const int c = ky*CPR + r;
      const int kk0 = r*32 + sub*8;
      const int kx = kk0 / IC;
      const int icoff = kk0 % IC;
      short8v B[WN];
#pragma unroll
      for (int n = 0; n < WN; n++)
        B[n] = *(const short8v*)(wbase + ((size_t)c*OC + oc0 + n*16 + l15)*32 + sub*8);
      short8v A[WM];
#pragma unroll
      for (int f = 0; f < WM; f++) {
        int iy = S*oyf[f] + ky + PADOFF;
        A[f] = *(const short8v*)(inb + ((size_t)iy*IPW + ixb[f] + kx)*IC + icoff);
      }
#pragma unroll
      for (int f = 0; f < WM; f++)
#pragma unroll
        for (int n = 0; n < WN; n++)
          acc[f][n] = __builtin_amdgcn_mfma_f32_16x16x32_bf16(A[f], B[n], acc[f][n], 0, 0, 0);
    }
  }

  // epilogue: +bias, store bf16 interior, accumulate BN partials
  float s[WN], q[WN];
#pragma unroll
  for (int n = 0; n < WN; n++) { s[n] = 0.f; q[n] = 0.f; }
#pragma unroll
  for (int f = 0; f < WM; f++) {
    const int oxs = oxb[f] + sub*4;
    const size_t rowb = ((size_t)b*OPH + oyf[f] + 2)*OPW;
#pragma unroll
    for (int n = 0; n < WN; n++) {
      int oc = oc0 + n*16 + l15;
      float bv = bias[oc];
#pragma unroll
      for (int rr = 0; rr < 4; rr++) {
        float v = acc[f][n][rr] + bv;
        out[(rowb + oxs + rr + 2)*OC + oc] = f2bf(v);
        s[n] += v; q[n] += v*v;
      }
    }
  }
#pragma unroll
  for (int n = 0; n < WN; n++) {
    s[n] += __shfl_xor(s[n], 16); s[n] += __shfl_xor(s[n], 32);
    q[n] += __shfl_xor(q[n], 16); q[n] += __shfl_xor(q[n], 32);
  }
  __shared__ float sred[WVM*WVN][WN][16][2];
  if (sub == 0) {
#pragma unroll
    for (int n = 0; n < WN; n++) { sred[w][n][l15][0] = s[n]; sred[w][n][l15][1] = q[n]; }
  }
  __syncthreads();
  const int NBp = gridDim.x * gridDim.z;
  const int pb = blockIdx.z * gridDim.x + blockIdx.x;
  const int tot = WVN*WN*16;
  if (tid < tot) {
    int c16 = tid & 15, n = (tid >> 4) % WN, wn2 = tid / (16*WN);
    float S_ = 0.f, Q_ = 0.f;
    for (int wm2 = 0; wm2 < WVM; wm2++) {
      S_ += sred[wn2*WVM + wm2][n][c16][0];
      Q_ += sred[wn2*WVM + wm2][n][c16][1];
    }
    int c = blockIdx.y*(16*WN*WVN) + wn2*(16*WN) + n*16 + c16;
    part2[(size_t)c*NBp + pb] = make_float2(S_, Q_);
  }
}

// ---------------------------------------------------------------------------
// BN stage2: reduce per-block partials -> (scale, shift)
// ---------------------------------------------------------------------------
__global__ void bn_stage2(const float2* __restrict__ part2, const float* __restrict__ g,
                          const float* __restrict__ bb, float* __restrict__ stats,
                          int NBp, float invN) {
  int c = blockIdx.x;
  float s = 0.f, q = 0.f;
  for (int i = threadIdx.x; i < NBp; i += 64) {
    float2 p = part2[(size_t)c*NBp + i];
    s += p.x; q += p.y;
  }
  for (int o = 32; o > 0; o >>= 1) { s += __shfl_down(s, o); q += __shfl_down(q, o); }
  if (threadIdx.x == 0) {
    float m = s * invN;
    float var = q * invN - m*m;
    float sc = g[c] * rsqrtf(var + BN_EPS);
    stats[2*c] = sc;
    stats[2*c+1] = bb[c] - m*sc;
  }
}

// bn finalize in place over PADDED buffer: interior -> affine+lrelu, pads -> 0
template <int C, int PH, int PW, int HH, int WW>
__global__ __launch_bounds__(256) void bn_fin(u16* __restrict__ y, const float* __restrict__ stats,
                                              int total8) {
  int i = blockIdx.x*256 + threadIdx.x;
  if (i >= total8) return;
  size_t e = (size_t)i*8;
  int c0 = (int)(e & (C-1));
  int px = (int)(e / C);
  int xx = px % PW;
  int yy = (px / PW) % PH;
  bool interior = (yy >= 2) & (yy < 2+HH) & (xx >= 2) & (xx < 2+WW);
  short8v u = *(short8v*)(y + e);
  short8v o;
#pragma unroll
  for (int j = 0; j < 8; j++) {
    float v = bf2f((u16)u[j]) * stats[2*(c0+j)] + stats[2*(c0+j)+1];
    o[j] = interior ? (short)f2bf(lrelu(v)) : (short)0;
  }
  *(short8v*)(y + e) = o;
}

// final: lrelu(bn(y6pad interior)) NHWC bf16 -> NCHW fp32 d_out
__global__ __launch_bounds__(256) void out_k(const u16* __restrict__ y6,
                                             const float* __restrict__ stats,
                                             float* __restrict__ out) {
  int i = blockIdx.x*256 + threadIdx.x;
  if (i >= 131072) return;
  size_t e = (size_t)i*4;
  int c0 = (int)(e & 127);
  int px = (int)(e >> 7);
  int loc = px & 255, b = px >> 8;
  int y = loc >> 4, x = loc & 15;
  const u16* src = y6 + (((size_t)b*20 + y + 2)*20 + x + 2)*128 + c0;
  ushort4 u = *(const ushort4*)src;
  float vv[4] = {bf2f(u.x), bf2f(u.y), bf2f(u.z), bf2f(u.w)};
#pragma unroll
  for (int j = 0; j < 4; j++) {
    int c = c0 + j;
    float v = vv[j] * stats[2*c] + stats[2*c+1];
    out[(((size_t)b*128 + c) << 8) + loc] = lrelu(v);
  }
}

// ---------------------------------------------------------------------------
extern "C" void kernel_launch(void* const* d_in, const int* in_sizes, int n_in,
                              void* d_out, int out_size, void* d_ws, size_t ws_size,
                              hipStream_t stream) {
  const float* x    = (const float*)d_in[0];
  const float* cw   = (const float*)d_in[1];
  const float* w11  = (const float*)d_in[2];
  const float* b11  = (const float*)d_in[3];
  const float* w12  = (const float*)d_in[4];
  const float* b12  = (const float*)d_in[5];
  const float* bn1g = (const float*)d_in[6];
  const float* bn1b = (const float*)d_in[7];
  const float* c2w[4] = {(const float*)d_in[8], (const float*)d_in[12],
                         (const float*)d_in[16], (const float*)d_in[20]};
  const float* c2b[4] = {(const float*)d_in[9], (const float*)d_in[13],
                         (const float*)d_in[17], (const float*)d_in[21]};
  const float* bng[4] = {(const float*)d_in[10], (const float*)d_in[14],
                         (const float*)d_in[18], (const float*)d_in[22]};
  const float* bnb[4] = {(const float*)d_in[11], (const float*)d_in[15],
                         (const float*)d_in[19], (const float*)d_in[23]};

  char* ws = (char*)d_ws;
  // Region A [0, 68.16MB): h1pad during L1/L2; then y3..y6 pads (S1..S4 phase).
  u16* h1   = (u16*)(ws);                          // 16x516x516x8  = 68,158,464 B
  u16* y3   = (u16*)(ws);                          // 16x132x132x32 = 17,842,176
  u16* y4   = (u16*)(ws + 17842176);               // 16x68x68x64   =  9,469,952
  u16* y5   = (u16*)(ws + 27312128);               // 16x36x36x128  =  5,308,416
  u16* y6   = (u16*)(ws + 32620544);               // 16x20x20x128  =  1,638,400
  // Region B [68.16MB, 102.77MB): yT2pad.
  u16* yT2  = (u16*)(ws + 68158464);               // 16x260x260x16 = 34,611,200
  // Tail [102.77MB, 104.14MB): everything with whole-run lifetime.
  u16* wl2m = (u16*)(ws + 102769664);              // 163,840
  float* bl2    = (float*)(ws + 102933504);        // 64
  float2* part2 = (float2*)(ws + 102933568);       // 524,288
  float* stats2 = (float*)(ws + 103457856);        // stats total 2,944
  float* stats3 = stats2 + 32;
  float* stats4 = stats3 + 64;
  float* stats5 = stats4 + 128;
  float* stats6 = stats5 + 256;
  u16* wl1d = (u16*)(ws + 103460800);              // 98,304 -> ends 103,559,104
  u16* wS1  = (u16*)(ws + 103559104);              // 30,720
  u16* wS2  = (u16*)(ws + 103589824);              // 102,400
  u16* wS3  = (u16*)(ws + 103692224);              // 147,456
  u16* wS4  = (u16*)(ws + 103839680);              // 294,912 -> ends 104,134,592

  prep_all<<<1894, 256, 0, stream>>>(w11, w12, b12, cw,
                                     c2w[0], c2w[1], c2w[2], c2w[3],
                                     wl1d, wl2m, bl2, wS1, wS2, wS3, wS4, h1);

  // L1: 3->8 k5 s1 -> h1pad interior (post-lrelu), MFMA dual-row
  conv_l1<<<dim3(512, 1, 16), 256, 0, stream>>>(x, wl1d, b11, h1);

  // L2: 8->16 k5 s2, per-sample weights -> yT2pad (pre-BN) + partials
  conv_mfma<8,16,5,2,2, 2,10, 516,516, 8, 260,260, 4,1,4,1, true>
      <<<dim3(256,1,16), 256, 0, stream>>>(h1, wl2m, bl2, yT2, part2);

  bn_stage2<<<16, 64, 0, stream>>>(part2, bn1g, bn1b, stats2, 4096, 1.f/1048576.f);
  bn_fin<16,260,260,256,256><<<8450, 256, 0, stream>>>(yT2, stats2, 2163200);

  // S1: 16->32 k5 s2 -> y3pad
  conv_mfma<16,32,5,2,2, 3,15, 260,260, 7, 132,132, 2,2,4,1, false>
      <<<dim3(128,1,16), 256, 0, stream>>>(yT2, wS1, c2b[0], y3, part2);
  bn_stage2<<<32, 64, 0, stream>>>(part2, bng[0], bnb[0], stats3, 2048, 1.f/262144.f);
  bn_fin<32,132,132,128,128><<<4356, 256, 0, stream>>>(y3, stats3, 1115136);

  // S2: 32->64 k5 s2 -> y4pad
  conv_mfma<32,64,5,2,2, 5,25, 132,132, 6, 68,68, 2,2,2,2, false>
      <<<dim3(64,1,16), 256, 0, stream>>>(y3, wS2, c2b[1], y4, part2);
  bn_stage2<<<64, 64, 0, stream>>>(part2, bng[1], bnb[1], stats4, 1024, 1.f/65536.f);
  bn_fin<64,68,68,64,64><<<2312, 256, 0, stream>>>(y4, stats4, 591872);

  // S3: 64->128 k3 s2 -> y5pad
  conv_mfma<64,128,3,2,1, 6,18, 68,68, 5, 36,36, 2,2,2,2, false>
      <<<dim3(16,2,16), 256, 0, stream>>>(y4, wS3, c2b[2], y5, part2);
  bn_stage2<<<128, 64, 0, stream>>>(part2, bng[2], bnb[2], stats5, 256, 1.f/16384.f);
  bn_fin<128,36,36,32,32><<<1296, 256, 0, stream>>>(y5, stats5, 331776);

  // S4: 128->128 k3 s2 -> y6pad (pre-BN)
  conv_mfma<128,128,3,2,1, 12,36, 36,36, 4, 20,20, 2,2,1,2, false>
      <<<dim3(8,2,16), 128, 0, stream>>>(y5, wS4, c2b[3], y6, part2);
  bn_stage2<<<128, 64, 0, stream>>>(part2, bng[3], bnb[3], stats6, 128, 1.f/4096.f);

  out_k<<<512, 256, 0, stream>>>(y6, stats6, (float*)d_out);
}

// Round 9
// 268.157 us; speedup vs baseline: 1.2249x; 1.0132x over previous
//
#include <hip/hip_runtime.h>

// CNN encoder round 9 (= round 8 + NaN fix):
//  - FIX: zero sx tail pad (A-read overhang at tile row 19 / colb 63 reads it;
//    uninit LDS can be bf16 NaN -> 0*NaN=NaN in MFMA). Align sx to 16B.
//  - conv_mfma: double-buffered chunk pipeline (unchanged from R8).
//  - conv_l1: 16-row tiles, float4 interior staging (unchanged from R8).

typedef __attribute__((ext_vector_type(8))) short short8v;
typedef __attribute__((ext_vector_type(4))) float float4v;
typedef __attribute__((ext_vector_type(4))) unsigned short ushort4v;
typedef unsigned short u16;

#define LRELU_NEG 0.2f
#define BN_EPS 1e-5f

__device__ __forceinline__ float bf2f(u16 u){ union{unsigned i; float f;} v; v.i=(unsigned)u<<16; return v.f; }
__device__ __forceinline__ u16 f2bf(float f){ unsigned x=__float_as_uint(f); x += 0x7FFFu + ((x>>16)&1u); return (u16)(x>>16); }
__device__ __forceinline__ float lrelu(float v){ return v<0.f? LRELU_NEG*v : v; }

// ---------------------------------------------------------------------------
// prep_all: all weight packing + h1 pad zeroing + bl2, one kernel.
// ---------------------------------------------------------------------------
__device__ __forceinline__ void packw(int i, const float* __restrict__ w, u16* __restrict__ dst,
                                      int IC, int OC, int KSZ, int CPR) {
  int kq = i & 31, oc = (i>>5) % OC, c = i/(OC*32);
  int ky = c / CPR, r = c % CPR;
  int kk = r*32 + kq; int kx = kk / IC, ic = kk % IC;
  float v = (kx < KSZ) ? w[(((size_t)oc*IC + ic)*KSZ + ky)*KSZ + kx] : 0.f;
  dst[i] = f2bf(v);
}

__global__ __launch_bounds__(256) void prep_all(
    const float* __restrict__ w11, const float* __restrict__ w12,
    const float* __restrict__ b12, const float* __restrict__ cw,
    const float* __restrict__ wc1, const float* __restrict__ wc2,
    const float* __restrict__ wc3, const float* __restrict__ wc4,
    u16* __restrict__ wl1d, u16* __restrict__ wl2m, float* __restrict__ bl2,
    u16* __restrict__ d1, u16* __restrict__ d2, u16* __restrict__ d3, u16* __restrict__ d4,
    u16* __restrict__ h1) {
  int i = blockIdx.x*256 + threadIdx.x;
  if (i < 16) {
    bl2[i] = (i<8)? b12[i] : 0.f;
  } else if (i < 49168) {                        // wl1d [b][c6][row16][k32]
    int j = i - 16;
    int b = j / 3072, r = j % 3072;
    int c = r >> 9, r2 = r & 511;
    int row = r2 >> 5, kk = r2 & 31;
    int kx = kk >> 2, ic = kk & 3;
    int grp = row >> 3, oc = row & 7;
    int ky = c - grp;
    float v = 0.f;
    if (ic < 3 && kx < 5 && ky >= 0 && ky < 5)
      v = (oc < 4) ? w11[((oc*3+ic)*5+ky)*5+kx]
                   : cw[b*1900 + (oc-4)*75 + ic*25 + ky*5 + kx];
    wl1d[j] = f2bf(v);
  } else if (i < 131088) {                       // wl2m [b][c10][oc16][kq32]
    int j = i - 49168;
    int kq = j & 31, oc = (j>>5) & 15, c = (j>>9) % 10, b = j / 5120;
    int ky = c >> 1, r = c & 1;
    int kk = r*32 + kq; int kx = kk >> 3, ic = kk & 7;
    float v = 0.f;
    if (kx < 5)
      v = (oc < 8) ? w12[((oc*8+ic)*5+ky)*5+kx]
                   : cw[b*1900 + 300 + ((oc-8)*8+ic)*25 + ky*5 + kx];
    wl2m[j] = f2bf(v);
  } else if (i < 196880) {                       // zero h1pad frame
    int j = i - 131088;
    int b = j / 4112, p = j % 4112;
    int y, xx;
    if (p < 2064) { int r = p/516; y = (r<2)? r : 512+r; xx = p%516; }
    else          { int q = p-2064; int cidx = q&3; xx = (cidx<2)? cidx : 512+cidx; y = 2 + (q>>2); }
    short8v z = {0,0,0,0,0,0,0,0};
    *(short8v*)(h1 + (((size_t)b*516 + y)*516 + xx)*8) = z;
  } else if (i < 484624) {                       // shared-weight packs
    int j = i - 196880;
    if (j < 15360) packw(j, wc1, d1, 16, 32, 5, 3);
    else if (j < 66560) packw(j-15360, wc2, d2, 32, 64, 5, 5);
    else if (j < 140288) packw(j-66560, wc3, d3, 64, 128, 3, 6);
    else packw(j-140288, wc4, d4, 128, 128, 3, 12);
  }
}

// ---------------------------------------------------------------------------
// L1 via MFMA (operand-swapped, dual-row): 3->8 k5 s1 p2, per-sample weights.
// Block: 64 px x 16 rows; 4 waves, wave w owns px strip w*16.
// LDS x-tile [20 rows][72 cols][4 ch] bf16 (ch3=0), left pad 4; A-read offset
// +2 cols (kx 5..7 weights zero -> overhang inert; tail pad zeroed).
// ---------------------------------------------------------------------------
__global__ __launch_bounds__(256) void conv_l1(const float* __restrict__ x,
    const u16* __restrict__ wl1d, const float* __restrict__ b11,
    u16* __restrict__ h1) {
  __shared__ __align__(16) u16 sx[20*72*4 + 32];
  const int tid = threadIdx.x, b = blockIdx.z;
  const int x0 = (blockIdx.x & 7) * 64;
  const int r0 = (blockIdx.x >> 3) * 16;

  if (tid < 32) sx[20*72*4 + tid] = 0;   // zero tail pad (A-read overhang)

  const bool interior = (r0 >= 16) & (r0 <= 480) & (x0 >= 64) & (x0 <= 384);
  if (interior) {
    for (int e = tid; e < 360; e += 256) {
      int row = e / 18, cg = e % 18;
      size_t base = ((size_t)b*3*512 + r0 + row - 2)*512 + x0 + cg*4 - 4;
      float4v p0 = *(const float4v*)(x + base);
      float4v p1 = *(const float4v*)(x + base + 262144);
      float4v p2 = *(const float4v*)(x + base + 524288);
      short8v lo, hi;
#pragma unroll
      for (int j = 0; j < 2; j++) {
        lo[4*j+0] = (short)f2bf(p0[j]);   lo[4*j+1] = (short)f2bf(p1[j]);
        lo[4*j+2] = (short)f2bf(p2[j]);   lo[4*j+3] = 0;
        hi[4*j+0] = (short)f2bf(p0[j+2]); hi[4*j+1] = (short)f2bf(p1[j+2]);
        hi[4*j+2] = (short)f2bf(p2[j+2]); hi[4*j+3] = 0;
      }
      u16* dp = sx + (row*72 + cg*4)*4;
      *(short8v*)dp = lo;
      *(short8v*)(dp + 8) = hi;
    }
  } else {
    for (int e = tid; e < 1440; e += 256) {
      int row = e / 72, col = e % 72;
      int gy = r0 + row - 2, gx = x0 + col - 4;
      float v0 = 0.f, v1 = 0.f, v2 = 0.f;
      if (gy >= 0 && gy < 512 && gx >= 0 && gx < 512) {
        size_t base = ((size_t)b*3*512 + gy)*512 + gx;
        v0 = x[base]; v1 = x[base + 262144]; v2 = x[base + 524288];
      }
      ushort4 pk = {f2bf(v0), f2bf(v1), f2bf(v2), 0};
      *(ushort4*)(sx + e*4) = pk;
    }
  }
  __syncthreads();

  const int lane = tid & 63, w = tid >> 6;
  const int l15 = lane & 15, sub = lane >> 4;

  short8v Wf[6];
  const u16* wb = wl1d + (size_t)b*3072;
#pragma unroll
  for (int c = 0; c < 6; c++)
    Wf[c] = *(const short8v*)(wb + (c*16 + l15)*32 + sub*8);

  float bvv[4];
#pragma unroll
  for (int r = 0; r < 4; r++) bvv[r] = (sub & 1) ? 0.f : b11[r];

  const int colb = w*16 + l15;
  const int oc0 = (sub & 1) * 4;
  const int rsel = sub >> 1;

#pragma unroll
  for (int p = 0; p < 8; p++) {
    float4v acc = {0.f, 0.f, 0.f, 0.f};
#pragma unroll
    for (int c = 0; c < 6; c++) {
      const u16* ap = sx + (((2*p + c)*72 + colb + 2) << 2) + sub*8;
      union { unsigned long long q[2]; short8v v; } ua;
      ua.q[0] = *(const unsigned long long*)(ap);
      ua.q[1] = *(const unsigned long long*)(ap + 4);
      acc = __builtin_amdgcn_mfma_f32_16x16x32_bf16(Wf[c], ua.v, acc, 0, 0, 0);
    }
    ushort4v pk;
#pragma unroll
    for (int r = 0; r < 4; r++) pk[r] = f2bf(lrelu(acc[r] + bvv[r]));
    int outrow = r0 + 2*p + rsel;
    u16* dst = h1 + (((size_t)b*516 + outrow + 2)*516 + x0 + colb + 2)*8 + oc0;
    *(ushort4v*)dst = pk;
  }
}

// ---------------------------------------------------------------------------
// Implicit-GEMM MFMA conv over PADDED NHWC input (no bounds checks),
// double-buffered chunk pipeline. Writes padded output interior (pre-BN,
// +bias) and per-block BN partials.
// ---------------------------------------------------------------------------
#define LOADC(cc, Ax, Bx) do {                                                   \
    const int ky_ = (cc) / CPR, r_ = (cc) % CPR;                                 \
    const int kk0_ = r_*32 + sub*8;                                              \
    const int kx_ = kk0_ / IC, ico_ = kk0_ % IC;                                 \
    _Pragma("unroll") for (int n_ = 0; n_ < WN; n_++)                            \
      Bx[n_] = *(const short8v*)(wbase + ((size_t)(cc)*OC + oc0 + n_*16 + l15)*32 + sub*8); \
    _Pragma("unroll") for (int f_ = 0; f_ < WM; f_++) {                          \
      int iy_ = S*oyf[f_] + ky_ + PADOFF;                                        \
      Ax[f_] = *(const short8v*)(inb + ((size_t)iy_*IPW + ixb[f_] + kx_)*IC + ico_); \
    }                                                                            \
  } while(0)

#define MFMAC(Ax, Bx) do {                                                       \
    _Pragma("unroll") for (int f_ = 0; f_ < WM; f_++)                            \
      _Pragma("unroll") for (int n_ = 0; n_ < WN; n_++)                          \
        acc[f_][n_] = __builtin_amdgcn_mfma_f32_16x16x32_bf16(Ax[f_], Bx[n_], acc[f_][n_], 0, 0, 0); \
  } while(0)

template <int IC, int OC, int KSZ, int S, int P, int CPR, int NCH,
          int IPH, int IPW, int OWL, int OPH, int OPW,
          int WM, int WN, int WVM, int WVN, bool PERS>
__global__ __launch_bounds__(WVM*WVN*64) void conv_mfma(
    const u16* __restrict__ in, const u16* __restrict__ wmfma,
    const float* __restrict__ bias, u16* __restrict__ out,
    float2* __restrict__ part2) {
  constexpr int OW = 1 << OWL;
  constexpr int PADOFF = 2 - P;
  const int tid = threadIdx.x, lane = tid & 63;
  const int w = tid >> 6, wm = w % WVM, wn = w / WVM;
  const int l15 = lane & 15, sub = lane >> 4;
  const int b = blockIdx.z;
  const int px0 = blockIdx.x * (16*WM*WVM) + wm * (16*WM);
  const int oc0 = blockIdx.y * (16*WN*WVN) + wn * (16*WN);

  int oyf[WM], oxb[WM], ixb[WM];
#pragma unroll
  for (int f = 0; f < WM; f++) {
    int p = px0 + f*16;
    oyf[f] = p >> OWL;
    oxb[f] = p & (OW-1);
    ixb[f] = S*(oxb[f] + l15) + PADOFF;
  }
  const u16* inb = in + (size_t)b*IPH*IPW*IC;
  const u16* wbase = wmfma + (PERS ? (size_t)b*NCH*OC*32 : (size_t)0);

  float4v acc[WM][WN];
#pragma unroll
  for (int f = 0; f < WM; f++)
#pragma unroll
    for (int n = 0; n < WN; n++) acc[f][n] = (float4v){0.f,0.f,0.f,0.f};

  constexpr int NC = KSZ * CPR;
  short8v A0[WM], B0[WN], A1[WM], B1[WN];
  LOADC(0, A0, B0);
#pragma unroll
  for (int c = 0; c < NC; c += 2) {
    if (c + 1 < NC) LOADC(c + 1, A1, B1);
    MFMAC(A0, B0);
    if (c + 2 < NC) LOADC(c + 2, A0, B0);
    if (c + 1 < NC) MFMAC(A1, B1);
  }

  // epilogue: +bias, store bf16 interior, accumulate BN partials
  float s[WN], q[WN];
#pragma unroll
  for (int n = 0; n < WN; n++) { s[n] = 0.f; q[n] = 0.f; }
#pragma unroll
  for (int f = 0; f < WM; f++) {
    const int oxs = oxb[f] + sub*4;
    const size_t rowb = ((size_t)b*OPH + oyf[f] + 2)*OPW;
#pragma unroll
    for (int n = 0; n < WN; n++) {
      int oc = oc0 + n*16 + l15;
      float bv = bias[oc];
#pragma unroll
      for (int rr = 0; rr < 4; rr++) {
        float v = acc[f][n][rr] + bv;
        out[(rowb + oxs + rr + 2)*OC + oc] = f2bf(v);
        s[n] += v; q[n] += v*v;
      }
    }
  }
#pragma unroll
  for (int n = 0; n < WN; n++) {
    s[n] += __shfl_xor(s[n], 16); s[n] += __shfl_xor(s[n], 32);
    q[n] += __shfl_xor(q[n], 16); q[n] += __shfl_xor(q[n], 32);
  }
  __shared__ float sred[WVM*WVN][WN][16][2];
  if (sub == 0) {
#pragma unroll
    for (int n = 0; n < WN; n++) { sred[w][n][l15][0] = s[n]; sred[w][n][l15][1] = q[n]; }
  }
  __syncthreads();
  const int NBp = gridDim.x * gridDim.z;
  const int pb = blockIdx.z * gridDim.x + blockIdx.x;
  const int tot = WVN*WN*16;
  if (tid < tot) {
    int c16 = tid & 15, n = (tid >> 4) % WN, wn2 = tid / (16*WN);
    float S_ = 0.f, Q_ = 0.f;
    for (int wm2 = 0; wm2 < WVM; wm2++) {
      S_ += sred[wn2*WVM + wm2][n][c16][0];
      Q_ += sred[wn2*WVM + wm2][n][c16][1];
    }
    int c = blockIdx.y*(16*WN*WVN) + wn2*(16*WN) + n*16 + c16;
    part2[(size_t)c*NBp + pb] = make_float2(S_, Q_);
  }
}

// ---------------------------------------------------------------------------
// BN stage2: reduce per-block partials -> (scale, shift)
// ---------------------------------------------------------------------------
__global__ void bn_stage2(const float2* __restrict__ part2, const float* __restrict__ g,
                          const float* __restrict__ bb, float* __restrict__ stats,
                          int NBp, float invN) {
  int c = blockIdx.x;
  float s = 0.f, q = 0.f;
  for (int i = threadIdx.x; i < NBp; i += 64) {
    float2 p = part2[(size_t)c*NBp + i];
    s += p.x; q += p.y;
  }
  for (int o = 32; o > 0; o >>= 1) { s += __shfl_down(s, o); q += __shfl_down(q, o); }
  if (threadIdx.x == 0) {
    float m = s * invN;
    float var = q * invN - m*m;
    float sc = g[c] * rsqrtf(var + BN_EPS);
    stats[2*c] = sc;
    stats[2*c+1] = bb[c] - m*sc;
  }
}

// bn finalize in place over PADDED buffer: interior -> affine+lrelu, pads -> 0
template <int C, int PH, int PW, int HH, int WW>
__global__ __launch_bounds__(256) void bn_fin(u16* __restrict__ y, const float* __restrict__ stats,
                                              int total8) {
  int i = blockIdx.x*256 + threadIdx.x;
  if (i >= total8) return;
  size_t e = (size_t)i*8;
  int c0 = (int)(e & (C-1));
  int px = (int)(e / C);
  int xx = px % PW;
  int yy = (px / PW) % PH;
  bool interior = (yy >= 2) & (yy < 2+HH) & (xx >= 2) & (xx < 2+WW);
  short8v u = *(short8v*)(y + e);
  short8v o;
#pragma unroll
  for (int j = 0; j < 8; j++) {
    float v = bf2f((u16)u[j]) * stats[2*(c0+j)] + stats[2*(c0+j)+1];
    o[j] = interior ? (short)f2bf(lrelu(v)) : (short)0;
  }
  *(short8v*)(y + e) = o;
}

// final: lrelu(bn(y6pad interior)) NHWC bf16 -> NCHW fp32 d_out
__global__ __launch_bounds__(256) void out_k(const u16* __restrict__ y6,
                                             const float* __restrict__ stats,
                                             float* __restrict__ out) {
  int i = blockIdx.x*256 + threadIdx.x;
  if (i >= 131072) return;
  size_t e = (size_t)i*4;
  int c0 = (int)(e & 127);
  int px = (int)(e >> 7);
  int loc = px & 255, b = px >> 8;
  int y = loc >> 4, x = loc & 15;
  const u16* src = y6 + (((size_t)b*20 + y + 2)*20 + x + 2)*128 + c0;
  ushort4 u = *(const ushort4*)src;
  float vv[4] = {bf2f(u.x), bf2f(u.y), bf2f(u.z), bf2f(u.w)};
#pragma unroll
  for (int j = 0; j < 4; j++) {
    int c = c0 + j;
    float v = vv[j] * stats[2*c] + stats[2*c+1];
    out[(((size_t)b*128 + c) << 8) + loc] = lrelu(v);
  }
}

// ---------------------------------------------------------------------------
extern "C" void kernel_launch(void* const* d_in, const int* in_sizes, int n_in,
                              void* d_out, int out_size, void* d_ws, size_t ws_size,
                              hipStream_t stream) {
  const float* x    = (const float*)d_in[0];
  const float* cw   = (const float*)d_in[1];
  const float* w11  = (const float*)d_in[2];
  const float* b11  = (const float*)d_in[3];
  const float* w12  = (const float*)d_in[4];
  const float* b12  = (const float*)d_in[5];
  const float* bn1g = (const float*)d_in[6];
  const float* bn1b = (const float*)d_in[7];
  const float* c2w[4] = {(const float*)d_in[8], (const float*)d_in[12],
                         (const float*)d_in[16], (const float*)d_in[20]};
  const float* c2b[4] = {(const float*)d_in[9], (const float*)d_in[13],
                         (const float*)d_in[17], (const float*)d_in[21]};
  const float* bng[4] = {(const float*)d_in[10], (const float*)d_in[14],
                         (const float*)d_in[18], (const float*)d_in[22]};
  const float* bnb[4] = {(const float*)d_in[11], (const float*)d_in[15],
                         (const float*)d_in[19], (const float*)d_in[23]};

  char* ws = (char*)d_ws;
  // Region A [0, 68.16MB): h1pad during L1/L2; then y3..y6 pads (S1..S4 phase).
  u16* h1   = (u16*)(ws);                          // 16x516x516x8  = 68,158,464 B
  u16* y3   = (u16*)(ws);                          // 16x132x132x32 = 17,842,176
  u16* y4   = (u16*)(ws + 17842176);               // 16x68x68x64   =  9,469,952
  u16* y5   = (u16*)(ws + 27312128);               // 16x36x36x128  =  5,308,416
  u16* y6   = (u16*)(ws + 32620544);               // 16x20x20x128  =  1,638,400
  // Region B [68.16MB, 102.77MB): yT2pad.
  u16* yT2  = (u16*)(ws + 68158464);               // 16x260x260x16 = 34,611,200
  // Tail [102.77MB, 104.14MB): everything with whole-run lifetime.
  u16* wl2m = (u16*)(ws + 102769664);              // 163,840
  float* bl2    = (float*)(ws + 102933504);        // 64
  float2* part2 = (float2*)(ws + 102933568);       // 524,288
  float* stats2 = (float*)(ws + 103457856);        // stats total 2,944
  float* stats3 = stats2 + 32;
  float* stats4 = stats3 + 64;
  float* stats5 = stats4 + 128;
  float* stats6 = stats5 + 256;
  u16* wl1d = (u16*)(ws + 103460800);              // 98,304 -> ends 103,559,104
  u16* wS1  = (u16*)(ws + 103559104);              // 30,720
  u16* wS2  = (u16*)(ws + 103589824);              // 102,400
  u16* wS3  = (u16*)(ws + 103692224);              // 147,456
  u16* wS4  = (u16*)(ws + 103839680);              // 294,912 -> ends 104,134,592

  prep_all<<<1894, 256, 0, stream>>>(w11, w12, b12, cw,
                                     c2w[0], c2w[1], c2w[2], c2w[3],
                                     wl1d, wl2m, bl2, wS1, wS2, wS3, wS4, h1);

  // L1: 3->8 k5 s1 -> h1pad interior (post-lrelu), MFMA dual-row, 16-row tiles
  conv_l1<<<dim3(256, 1, 16), 256, 0, stream>>>(x, wl1d, b11, h1);

  // L2: 8->16 k5 s2, per-sample weights -> yT2pad (pre-BN) + partials
  conv_mfma<8,16,5,2,2, 2,10, 516,516, 8, 260,260, 4,1,4,1, true>
      <<<dim3(256,1,16), 256, 0, stream>>>(h1, wl2m, bl2, yT2, part2);

  bn_stage2<<<16, 64, 0, stream>>>(part2, bn1g, bn1b, stats2, 4096, 1.f/1048576.f);
  bn_fin<16,260,260,256,256><<<8450, 256, 0, stream>>>(yT2, stats2, 2163200);

  // S1: 16->32 k5 s2 -> y3pad
  conv_mfma<16,32,5,2,2, 3,15, 260,260, 7, 132,132, 2,2,4,1, false>
      <<<dim3(128,1,16), 256, 0, stream>>>(yT2, wS1, c2b[0], y3, part2);
  bn_stage2<<<32, 64, 0, stream>>>(part2, bng[0], bnb[0], stats3, 2048, 1.f/262144.f);
  bn_fin<32,132,132,128,128><<<4356, 256, 0, stream>>>(y3, stats3, 1115136);

  // S2: 32->64 k5 s2 -> y4pad
  conv_mfma<32,64,5,2,2, 5,25, 132,132, 6, 68,68, 2,2,2,2, false>
      <<<dim3(64,1,16), 256, 0, stream>>>(y3, wS2, c2b[1], y4, part2);
  bn_stage2<<<64, 64, 0, stream>>>(part2, bng[1], bnb[1], stats4, 1024, 1.f/65536.f);
  bn_fin<64,68,68,64,64><<<2312, 256, 0, stream>>>(y4, stats4, 591872);

  // S3: 64->128 k3 s2 -> y5pad
  conv_mfma<64,128,3,2,1, 6,18, 68,68, 5, 36,36, 2,2,2,2, false>
      <<<dim3(16,2,16), 256, 0, stream>>>(y4, wS3, c2b[2], y5, part2);
  bn_stage2<<<128, 64, 0, stream>>>(part2, bng[2], bnb[2], stats5, 256, 1.f/16384.f);
  bn_fin<128,36,36,32,32><<<1296, 256, 0, stream>>>(y5, stats5, 331776);

  // S4: 128->128 k3 s2 -> y6pad (pre-BN)
  conv_mfma<128,128,3,2,1, 12,36, 36,36, 4, 20,20, 2,2,1,2, false>
      <<<dim3(8,2,16), 128, 0, stream>>>(y5, wS4, c2b[3], y6, part2);
  bn_stage2<<<128, 64, 0, stream>>>(part2, bng[3], bnb[3], stats6, 128, 1.f/4096.f);

  out_k<<<512, 256, 0, stream>>>(y6, stats6, (float*)d_out);
}

// Round 10
// 252.565 us; speedup vs baseline: 1.3005x; 1.0617x over previous
//
#include <hip/hip_runtime.h>

// CNN encoder round 10:
//  - PARITY-SPLIT activation layout [H][2][W/2][C] (even/odd x planes).
//    All convs have stride 2: ix = 2*ox + t -> plane t&1, pos ox + (t>>1),
//    so A-load lanes are CONTIGUOUS (was stride S*IC*2 = 32..256 B scatter).
//  - conv_mfma load/store, conv_l1 store, h1 pad-zero, bn_fin, out_k updated.
//  - everything else identical to round 9.

typedef __attribute__((ext_vector_type(8))) short short8v;
typedef __attribute__((ext_vector_type(4))) float float4v;
typedef __attribute__((ext_vector_type(4))) unsigned short ushort4v;
typedef unsigned short u16;

#define LRELU_NEG 0.2f
#define BN_EPS 1e-5f

__device__ __forceinline__ float bf2f(u16 u){ union{unsigned i; float f;} v; v.i=(unsigned)u<<16; return v.f; }
__device__ __forceinline__ u16 f2bf(float f){ unsigned x=__float_as_uint(f); x += 0x7FFFu + ((x>>16)&1u); return (u16)(x>>16); }
__device__ __forceinline__ float lrelu(float v){ return v<0.f? LRELU_NEG*v : v; }

// ---------------------------------------------------------------------------
// prep_all: all weight packing + h1 pad zeroing + bl2, one kernel.
// ---------------------------------------------------------------------------
__device__ __forceinline__ void packw(int i, const float* __restrict__ w, u16* __restrict__ dst,
                                      int IC, int OC, int KSZ, int CPR) {
  int kq = i & 31, oc = (i>>5) % OC, c = i/(OC*32);
  int ky = c / CPR, r = c % CPR;
  int kk = r*32 + kq; int kx = kk / IC, ic = kk % IC;
  float v = (kx < KSZ) ? w[(((size_t)oc*IC + ic)*KSZ + ky)*KSZ + kx] : 0.f;
  dst[i] = f2bf(v);
}

__global__ __launch_bounds__(256) void prep_all(
    const float* __restrict__ w11, const float* __restrict__ w12,
    const float* __restrict__ b12, const float* __restrict__ cw,
    const float* __restrict__ wc1, const float* __restrict__ wc2,
    const float* __restrict__ wc3, const float* __restrict__ wc4,
    u16* __restrict__ wl1d, u16* __restrict__ wl2m, float* __restrict__ bl2,
    u16* __restrict__ d1, u16* __restrict__ d2, u16* __restrict__ d3, u16* __restrict__ d4,
    u16* __restrict__ h1) {
  int i = blockIdx.x*256 + threadIdx.x;
  if (i < 16) {
    bl2[i] = (i<8)? b12[i] : 0.f;
  } else if (i < 49168) {                        // wl1d [b][c6][row16][k32]
    int j = i - 16;
    int b = j / 3072, r = j % 3072;
    int c = r >> 9, r2 = r & 511;
    int row = r2 >> 5, kk = r2 & 31;
    int kx = kk >> 2, ic = kk & 3;
    int grp = row >> 3, oc = row & 7;
    int ky = c - grp;
    float v = 0.f;
    if (ic < 3 && kx < 5 && ky >= 0 && ky < 5)
      v = (oc < 4) ? w11[((oc*3+ic)*5+ky)*5+kx]
                   : cw[b*1900 + (oc-4)*75 + ic*25 + ky*5 + kx];
    wl1d[j] = f2bf(v);
  } else if (i < 131088) {                       // wl2m [b][c10][oc16][kq32]
    int j = i - 49168;
    int kq = j & 31, oc = (j>>5) & 15, c = (j>>9) % 10, b = j / 5120;
    int ky = c >> 1, r = c & 1;
    int kk = r*32 + kq; int kx = kk >> 3, ic = kk & 7;
    float v = 0.f;
    if (kx < 5)
      v = (oc < 8) ? w12[((oc*8+ic)*5+ky)*5+kx]
                   : cw[b*1900 + 300 + ((oc-8)*8+ic)*25 + ky*5 + kx];
    wl2m[j] = f2bf(v);
  } else if (i < 196880) {                       // zero h1pad frame (parity layout)
    int j = i - 131088;
    int b = j / 4112, p = j % 4112;
    int y, xx;
    if (p < 2064) { int r = p/516; y = (r<2)? r : 512+r; xx = p%516; }
    else          { int q = p-2064; int cidx = q&3; xx = (cidx<2)? cidx : 512+cidx; y = 2 + (q>>2); }
    short8v z = {0,0,0,0,0,0,0,0};
    *(short8v*)(h1 + ((((size_t)b*516 + y)*2 + (xx&1))*258 + (xx>>1))*8) = z;
  } else if (i < 484624) {                       // shared-weight packs
    int j = i - 196880;
    if (j < 15360) packw(j, wc1, d1, 16, 32, 5, 3);
    else if (j < 66560) packw(j-15360, wc2, d2, 32, 64, 5, 5);
    else if (j < 140288) packw(j-66560, wc3, d3, 64, 128, 3, 6);
    else packw(j-140288, wc4, d4, 128, 128, 3, 12);
  }
}

// ---------------------------------------------------------------------------
// L1 via MFMA (operand-swapped, dual-row): 3->8 k5 s1 p2, per-sample weights.
// Block: 64 px x 16 rows; 4 waves, wave w owns px strip w*16.
// LDS x-tile [20 rows][72 cols][4 ch] bf16 (ch3=0), left pad 4; A-read offset
// +2 cols (kx 5..7 weights zero; tail pad zeroed). Writes h1 PARITY layout.
// ---------------------------------------------------------------------------
__global__ __launch_bounds__(256) void conv_l1(const float* __restrict__ x,
    const u16* __restrict__ wl1d, const float* __restrict__ b11,
    u16* __restrict__ h1) {
  __shared__ __align__(16) u16 sx[20*72*4 + 32];
  const int tid = threadIdx.x, b = blockIdx.z;
  const int x0 = (blockIdx.x & 7) * 64;
  const int r0 = (blockIdx.x >> 3) * 16;

  if (tid < 32) sx[20*72*4 + tid] = 0;   // zero tail pad (A-read overhang)

  const bool interior = (r0 >= 16) & (r0 <= 480) & (x0 >= 64) & (x0 <= 384);
  if (interior) {
    for (int e = tid; e < 360; e += 256) {
      int row = e / 18, cg = e % 18;
      size_t base = ((size_t)b*3*512 + r0 + row - 2)*512 + x0 + cg*4 - 4;
      float4v p0 = *(const float4v*)(x + base);
      float4v p1 = *(const float4v*)(x + base + 262144);
      float4v p2 = *(const float4v*)(x + base + 524288);
      short8v lo, hi;
#pragma unroll
      for (int j = 0; j < 2; j++) {
        lo[4*j+0] = (short)f2bf(p0[j]);   lo[4*j+1] = (short)f2bf(p1[j]);
        lo[4*j+2] = (short)f2bf(p2[j]);   lo[4*j+3] = 0;
        hi[4*j+0] = (short)f2bf(p0[j+2]); hi[4*j+1] = (short)f2bf(p1[j+2]);
        hi[4*j+2] = (short)f2bf(p2[j+2]); hi[4*j+3] = 0;
      }
      u16* dp = sx + (row*72 + cg*4)*4;
      *(short8v*)dp = lo;
      *(short8v*)(dp + 8) = hi;
    }
  } else {
    for (int e = tid; e < 1440; e += 256) {
      int row = e / 72, col = e % 72;
      int gy = r0 + row - 2, gx = x0 + col - 4;
      float v0 = 0.f, v1 = 0.f, v2 = 0.f;
      if (gy >= 0 && gy < 512 && gx >= 0 && gx < 512) {
        size_t base = ((size_t)b*3*512 + gy)*512 + gx;
        v0 = x[base]; v1 = x[base + 262144]; v2 = x[base + 524288];
      }
      ushort4 pk = {f2bf(v0), f2bf(v1), f2bf(v2), 0};
      *(ushort4*)(sx + e*4) = pk;
    }
  }
  __syncthreads();

  const int lane = tid & 63, w = tid >> 6;
  const int l15 = lane & 15, sub = lane >> 4;

  short8v Wf[6];
  const u16* wb = wl1d + (size_t)b*3072;
#pragma unroll
  for (int c = 0; c < 6; c++)
    Wf[c] = *(const short8v*)(wb + (c*16 + l15)*32 + sub*8);

  float bvv[4];
#pragma unroll
  for (int r = 0; r < 4; r++) bvv[r] = (sub & 1) ? 0.f : b11[r];

  const int colb = w*16 + l15;
  const int oc0 = (sub & 1) * 4;
  const int rsel = sub >> 1;
  const int x_out = x0 + colb + 2;
  const int xpar = x_out & 1, xp = x_out >> 1;

#pragma unroll
  for (int p = 0; p < 8; p++) {
    float4v acc = {0.f, 0.f, 0.f, 0.f};
#pragma unroll
    for (int c = 0; c < 6; c++) {
      const u16* ap = sx + (((2*p + c)*72 + colb + 2) << 2) + sub*8;
      union { unsigned long long q[2]; short8v v; } ua;
      ua.q[0] = *(const unsigned long long*)(ap);
      ua.q[1] = *(const unsigned long long*)(ap + 4);
      acc = __builtin_amdgcn_mfma_f32_16x16x32_bf16(Wf[c], ua.v, acc, 0, 0, 0);
    }
    ushort4v pk;
#pragma unroll
    for (int r = 0; r < 4; r++) pk[r] = f2bf(lrelu(acc[r] + bvv[r]));
    int outrow = r0 + 2*p + rsel;
    u16* dst = h1 + ((((size_t)b*516 + outrow + 2)*2 + xpar)*258 + xp)*8 + oc0;
    *(ushort4v*)dst = pk;
  }
}

// ---------------------------------------------------------------------------
// Implicit-GEMM MFMA conv over PARITY-SPLIT padded NHWC input (no bounds
// checks), double-buffered chunk pipeline. In/out layout [H][2][W/2][C].
// ix = 2*ox + kx + PADOFF = 2*(ox + t>>1) + (t&1). S must be 2.
// ---------------------------------------------------------------------------
#define LOADC(cc, Ax, Bx) do {                                                   \
    const int ky_ = (cc) / CPR, r_ = (cc) % CPR;                                 \
    const int kk0_ = r_*32 + sub*8;                                              \
    const int kx_ = kk0_ / IC, ico_ = kk0_ % IC;                                 \
    const int t_ = kx_ + PADOFF;                                                 \
    _Pragma("unroll") for (int n_ = 0; n_ < WN; n_++)                            \
      Bx[n_] = *(const short8v*)(wbase + ((size_t)(cc)*OC + oc0 + n_*16 + l15)*32 + sub*8); \
    _Pragma("unroll") for (int f_ = 0; f_ < WM; f_++) {                          \
      int iy_ = 2*oyf[f_] + ky_ + PADOFF;                                        \
      Ax[f_] = *(const short8v*)(inb + (((size_t)iy_*2 + (t_&1))*IPWH + axb[f_] + (t_>>1))*IC + ico_); \
    }                                                                            \
  } while(0)

#define MFMAC(Ax, Bx) do {                                                       \
    _Pragma("unroll") for (int f_ = 0; f_ < WM; f_++)                            \
      _Pragma("unroll") for (int n_ = 0; n_ < WN; n_++)                          \
        acc[f_][n_] = __builtin_amdgcn_mfma_f32_16x16x32_bf16(Ax[f_], Bx[n_], acc[f_][n_], 0, 0, 0); \
  } while(0)

template <int IC, int OC, int KSZ, int S, int P, int CPR, int NCH,
          int IPH, int IPW, int OWL, int OPH, int OPW,
          int WM, int WN, int WVM, int WVN, bool PERS>
__global__ __launch_bounds__(WVM*WVN*64) void conv_mfma(
    const u16* __restrict__ in, const u16* __restrict__ wmfma,
    const float* __restrict__ bias, u16* __restrict__ out,
    float2* __restrict__ part2) {
  constexpr int OW = 1 << OWL;
  constexpr int PADOFF = 2 - P;
  constexpr int IPWH = IPW / 2;
  constexpr int OPWH = OPW / 2;
  const int tid = threadIdx.x, lane = tid & 63;
  const int w = tid >> 6, wm = w % WVM, wn = w / WVM;
  const int l15 = lane & 15, sub = lane >> 4;
  const int b = blockIdx.z;
  const int px0 = blockIdx.x * (16*WM*WVM) + wm * (16*WM);
  const int oc0 = blockIdx.y * (16*WN*WVN) + wn * (16*WN);

  int oyf[WM], oxb[WM], axb[WM];
#pragma unroll
  for (int f = 0; f < WM; f++) {
    int p = px0 + f*16;
    oyf[f] = p >> OWL;
    oxb[f] = p & (OW-1);
    axb[f] = oxb[f] + l15;
  }
  const u16* inb = in + (size_t)b*IPH*IPW*IC;
  const u16* wbase = wmfma + (PERS ? (size_t)b*NCH*OC*32 : (size_t)0);

  float4v acc[WM][WN];
#pragma unroll
  for (int f = 0; f < WM; f++)
#pragma unroll
    for (int n = 0; n < WN; n++) acc[f][n] = (float4v){0.f,0.f,0.f,0.f};

  constexpr int NC = KSZ * CPR;
  short8v A0[WM], B0[WN], A1[WM], B1[WN];
  LOADC(0, A0, B0);
#pragma unroll
  for (int c = 0; c < NC; c += 2) {
    if (c + 1 < NC) LOADC(c + 1, A1, B1);
    MFMAC(A0, B0);
    if (c + 2 < NC) LOADC(c + 2, A0, B0);
    if (c + 1 < NC) MFMAC(A1, B1);
  }

  // epilogue: +bias, store bf16 interior (parity layout), BN partials
  float s[WN], q[WN];
#pragma unroll
  for (int n = 0; n < WN; n++) { s[n] = 0.f; q[n] = 0.f; }
#pragma unroll
  for (int f = 0; f < WM; f++) {
    const int oxs = oxb[f] + sub*4;
    const size_t rowb2 = ((size_t)b*OPH + oyf[f] + 2)*2;
#pragma unroll
    for (int n = 0; n < WN; n++) {
      int oc = oc0 + n*16 + l15;
      float bv = bias[oc];
#pragma unroll
      for (int rr = 0; rr < 4; rr++) {
        float v = acc[f][n][rr] + bv;
        int x_out = oxs + rr + 2;
        out[((rowb2 + (x_out & 1))*OPWH + (x_out >> 1))*OC + oc] = f2bf(v);
        s[n] += v; q[n] += v*v;
      }
    }
  }
#pragma unroll
  for (int n = 0; n < WN; n++) {
    s[n] += __shfl_xor(s[n], 16); s[n] += __shfl_xor(s[n], 32);
    q[n] += __shfl_xor(q[n], 16); q[n] += __shfl_xor(q[n], 32);
  }
  __shared__ float sred[WVM*WVN][WN][16][2];
  if (sub == 0) {
#pragma unroll
    for (int n = 0; n < WN; n++) { sred[w][n][l15][0] = s[n]; sred[w][n][l15][1] = q[n]; }
  }
  __syncthreads();
  const int NBp = gridDim.x * gridDim.z;
  const int pb = blockIdx.z * gridDim.x + blockIdx.x;
  const int tot = WVN*WN*16;
  if (tid < tot) {
    int c16 = tid & 15, n = (tid >> 4) % WN, wn2 = tid / (16*WN);
    float S_ = 0.f, Q_ = 0.f;
    for (int wm2 = 0; wm2 < WVM; wm2++) {
      S_ += sred[wn2*WVM + wm2][n][c16][0];
      Q_ += sred[wn2*WVM + wm2][n][c16][1];
    }
    int c = blockIdx.y*(16*WN*WVN) + wn2*(16*WN) + n*16 + c16;
    part2[(size_t)c*NBp + pb] = make_float2(S_, Q_);
  }
}

// ---------------------------------------------------------------------------
// BN stage2: reduce per-block partials -> (scale, shift)
// ---------------------------------------------------------------------------
__global__ void bn_stage2(const float2* __restrict__ part2, const float* __restrict__ g,
                          const float* __restrict__ bb, float* __restrict__ stats,
                          int NBp, float invN) {
  int c = blockIdx.x;
  float s = 0.f, q = 0.f;
  for (int i = threadIdx.x; i < NBp; i += 64) {
    float2 p = part2[(size_t)c*NBp + i];
    s += p.x; q += p.y;
  }
  for (int o = 32; o > 0; o >>= 1) { s += __shfl_down(s, o); q += __shfl_down(q, o); }
  if (threadIdx.x == 0) {
    float m = s * invN;
    float var = q * invN - m*m;
    float sc = g[c] * rsqrtf(var + BN_EPS);
    stats[2*c] = sc;
    stats[2*c+1] = bb[c] - m*sc;
  }
}

// bn finalize in place over PARITY-SPLIT padded buffer:
// interior -> affine+lrelu, pads -> 0. Buffer [PH][2][PW/2][C].
template <int C, int PH, int PW, int HH, int WW>
__global__ __launch_bounds__(256) void bn_fin(u16* __restrict__ y, const float* __restrict__ stats,
                                              int total8) {
  int i = blockIdx.x*256 + threadIdx.x;
  if (i >= total8) return;
  size_t e = (size_t)i*8;
  int c0 = (int)(e & (C-1));
  int px = (int)(e / C);
  int xp = px % (PW/2);
  int t2 = px / (PW/2);
  int yy = (t2 >> 1) % PH;
  bool interior = (yy >= 2) & (yy < 2+HH) & (xp >= 1) & (xp <= WW/2);
  short8v u = *(short8v*)(y + e);
  short8v o;
#pragma unroll
  for (int j = 0; j < 8; j++) {
    float v = bf2f((u16)u[j]) * stats[2*(c0+j)] + stats[2*(c0+j)+1];
    o[j] = interior ? (short)f2bf(lrelu(v)) : (short)0;
  }
  *(short8v*)(y + e) = o;
}

// final: lrelu(bn(y6pad interior)) parity NHWC bf16 -> NCHW fp32 d_out
__global__ __launch_bounds__(256) void out_k(const u16* __restrict__ y6,
                                             const float* __restrict__ stats,
                                             float* __restrict__ out) {
  int i = blockIdx.x*256 + threadIdx.x;
  if (i >= 131072) return;
  size_t e = (size_t)i*4;
  int c0 = (int)(e & 127);
  int px = (int)(e >> 7);
  int loc = px & 255, b = px >> 8;
  int y = loc >> 4, x = loc & 15;
  int xi = x + 2;
  const u16* src = y6 + ((((size_t)b*20 + y + 2)*2 + (xi & 1))*10 + (xi >> 1))*128 + c0;
  ushort4 u = *(const ushort4*)src;
  float vv[4] = {bf2f(u.x), bf2f(u.y), bf2f(u.z), bf2f(u.w)};
#pragma unroll
  for (int j = 0; j < 4; j++) {
    int c = c0 + j;
    float v = vv[j] * stats[2*c] + stats[2*c+1];
    out[(((size_t)b*128 + c) << 8) + loc] = lrelu(v);
  }
}

// ---------------------------------------------------------------------------
extern "C" void kernel_launch(void* const* d_in, const int* in_sizes, int n_in,
                              void* d_out, int out_size, void* d_ws, size_t ws_size,
                              hipStream_t stream) {
  const float* x    = (const float*)d_in[0];
  const float* cw   = (const float*)d_in[1];
  const float* w11  = (const float*)d_in[2];
  const float* b11  = (const float*)d_in[3];
  const float* w12  = (const float*)d_in[4];
  const float* b12  = (const float*)d_in[5];
  const float* bn1g = (const float*)d_in[6];
  const float* bn1b = (const float*)d_in[7];
  const float* c2w[4] = {(const float*)d_in[8], (const float*)d_in[12],
                         (const float*)d_in[16], (const float*)d_in[20]};
  const float* c2b[4] = {(const float*)d_in[9], (const float*)d_in[13],
                         (const float*)d_in[17], (const float*)d_in[21]};
  const float* bng[4] = {(const float*)d_in[10], (const float*)d_in[14],
                         (const float*)d_in[18], (const float*)d_in[22]};
  const float* bnb[4] = {(const float*)d_in[11], (const float*)d_in[15],
                         (const float*)d_in[19], (const float*)d_in[23]};

  char* ws = (char*)d_ws;
  // Region A [0, 68.16MB): h1pad during L1/L2; then y3..y6 pads (S1..S4 phase).
  u16* h1   = (u16*)(ws);                          // 16x516x2x258x8 = 68,158,464 B
  u16* y3   = (u16*)(ws);                          // 16x132x2x66x32 = 17,842,176
  u16* y4   = (u16*)(ws + 17842176);               // 16x68x2x34x64  =  9,469,952
  u16* y5   = (u16*)(ws + 27312128);               // 16x36x2x18x128 =  5,308,416
  u16* y6   = (u16*)(ws + 32620544);               // 16x20x2x10x128 =  1,638,400
  // Region B [68.16MB, 102.77MB): yT2pad.
  u16* yT2  = (u16*)(ws + 68158464);               // 16x260x2x130x16 = 34,611,200
  // Tail [102.77MB, 104.14MB): everything with whole-run lifetime.
  u16* wl2m = (u16*)(ws + 102769664);              // 163,840
  float* bl2    = (float*)(ws + 102933504);        // 64
  float2* part2 = (float2*)(ws + 102933568);       // 524,288
  float* stats2 = (float*)(ws + 103457856);        // stats total 2,944
  float* stats3 = stats2 + 32;
  float* stats4 = stats3 + 64;
  float* stats5 = stats4 + 128;
  float* stats6 = stats5 + 256;
  u16* wl1d = (u16*)(ws + 103460800);              // 98,304 -> ends 103,559,104
  u16* wS1  = (u16*)(ws + 103559104);              // 30,720
  u16* wS2  = (u16*)(ws + 103589824);              // 102,400
  u16* wS3  = (u16*)(ws + 103692224);              // 147,456
  u16* wS4  = (u16*)(ws + 103839680);              // 294,912 -> ends 104,134,592

  prep_all<<<1894, 256, 0, stream>>>(w11, w12, b12, cw,
                                     c2w[0], c2w[1], c2w[2], c2w[3],
                                     wl1d, wl2m, bl2, wS1, wS2, wS3, wS4, h1);

  // L1: 3->8 k5 s1 -> h1pad interior (post-lrelu), parity layout
  conv_l1<<<dim3(256, 1, 16), 256, 0, stream>>>(x, wl1d, b11, h1);

  // L2: 8->16 k5 s2, per-sample weights -> yT2pad (pre-BN) + partials
  conv_mfma<8,16,5,2,2, 2,10, 516,516, 8, 260,260, 4,1,4,1, true>
      <<<dim3(256,1,16), 256, 0, stream>>>(h1, wl2m, bl2, yT2, part2);

  bn_stage2<<<16, 64, 0, stream>>>(part2, bn1g, bn1b, stats2, 4096, 1.f/1048576.f);
  bn_fin<16,260,260,256,256><<<8450, 256, 0, stream>>>(yT2, stats2, 2163200);

  // S1: 16->32 k5 s2 -> y3pad
  conv_mfma<16,32,5,2,2, 3,15, 260,260, 7, 132,132, 2,2,4,1, false>
      <<<dim3(128,1,16), 256, 0, stream>>>(yT2, wS1, c2b[0], y3, part2);
  bn_stage2<<<32, 64, 0, stream>>>(part2, bng[0], bnb[0], stats3, 2048, 1.f/262144.f);
  bn_fin<32,132,132,128,128><<<4356, 256, 0, stream>>>(y3, stats3, 1115136);

  // S2: 32->64 k5 s2 -> y4pad
  conv_mfma<32,64,5,2,2, 5,25, 132,132, 6, 68,68, 2,2,2,2, false>
      <<<dim3(64,1,16), 256, 0, stream>>>(y3, wS2, c2b[1], y4, part2);
  bn_stage2<<<64, 64, 0, stream>>>(part2, bng[1], bnb[1], stats4, 1024, 1.f/65536.f);
  bn_fin<64,68,68,64,64><<<2312, 256, 0, stream>>>(y4, stats4, 591872);

  // S3: 64->128 k3 s2 -> y5pad
  conv_mfma<64,128,3,2,1, 6,18, 68,68, 5, 36,36, 2,2,2,2, false>
      <<<dim3(16,2,16), 256, 0, stream>>>(y4, wS3, c2b[2], y5, part2);
  bn_stage2<<<128, 64, 0, stream>>>(part2, bng[2], bnb[2], stats5, 256, 1.f/16384.f);
  bn_fin<128,36,36,32,32><<<1296, 256, 0, stream>>>(y5, stats5, 331776);

  // S4: 128->128 k3 s2 -> y6pad (pre-BN)
  conv_mfma<128,128,3,2,1, 12,36, 36,36, 4, 20,20, 2,2,1,2, false>
      <<<dim3(8,2,16), 128, 0, stream>>>(y5, wS4, c2b[3], y6, part2);
  bn_stage2<<<128, 64, 0, stream>>>(part2, bng[3], bnb[3], stats6, 128, 1.f/4096.f);

  out_k<<<512, 256, 0, stream>>>(y6, stats6, (float*)d_out);
}